// Round 7
// baseline (187.666 us; speedup 1.0000x reference)
//
#include <hip/hip_runtime.h>
#include <hip/hip_bf16.h>

// DenseContrastiveLossV2 on MI355X — round 8.
// Round-7 post-mortem: k_neg ~45us vs overlapped floor ~18-20us
// (LDS-read 14.8us, MFMA 15.7us, staging 7.4us). Gap = single-buffer
// serialization. Round-3's dbuf failed because the prefetch was issued
// BEFORE the barrier (implicit vmcnt(0) drained it immediately). Correct
// T3-minimum order: barrier -> issue prefetch(other buf) -> compute(cur);
// the prefetch drains at the NEXT barrier, one compute-phase later.
// K0 k_prep   : 64 blocks zero ns; block 0 builds scales + active-tile list.
// K1 k_gather : unchanged.
// K2 k_norm   : unchanged.
// K3 k_neg    : BM=128 x BN=64, 8 waves, af[2][8] resident, DOUBLE-buffered
//               B staging with barrier-then-issue order; exp2f-fused exp.
// K4 k_pos    : unchanged (list-driven, off-profile).

namespace {

constexpr int kC = 256;
constexpr int kHW = 96 * 96;   // 9216
constexpr int kT = 32;
constexpr int kV = 256;
constexpr int kM = kT * kV;    // 8192

typedef __attribute__((ext_vector_type(8))) short short8;  // 8 bf16
typedef __attribute__((ext_vector_type(4))) float f32x4;

__device__ inline unsigned short f2bf(float x) {
  __hip_bfloat16 h = __float2bfloat16(x);
  return __builtin_bit_cast(unsigned short, h);
}
__device__ inline float bf2f(unsigned short u) {
  unsigned int v = ((unsigned int)u) << 16;
  return __builtin_bit_cast(float, v);
}
__device__ inline void load_lds16(const unsigned short* g, unsigned short* l) {
  __builtin_amdgcn_global_load_lds(
      (const __attribute__((address_space(1))) void*)g,
      (__attribute__((address_space(3))) void*)l, 16, 0, 0);
}

// exp(2a-2) = exp2(a*2log2e - 2log2e); one fma + native v_exp_f32.
__device__ inline float exp_2am2(float a) {
  return exp2f(fmaf(a, 2.8853900818f, -2.8853900818f));
}

// Stage one 64-row x 256-k bf16 tile (32 KB) of F into LDS with 256 threads,
// XOR-swizzled (inverse-swizzled global source + linear LDS dst, so the
// swizzled ds_read is conflict-free).
__device__ inline void stage_tile4(const unsigned short* __restrict__ F,
                                   unsigned short* lds, int ct, int tid) {
#pragma unroll
  for (int i = 0; i < 8; ++i) {
    const int n = i * 256 + tid;               // 16B-slot 0..2047
    const int j = n >> 5;                      // row 0..63
    const int m = (n & 31) ^ (j & 31);         // swizzled 16B k-chunk
    load_lds16(F + ((size_t)(ct * 64 + j) << 8) + m * 8,
               lds + (size_t)n * 8);
  }
}

// Same, with 512 threads (8-wave blocks).
__device__ inline void stage_tile8(const unsigned short* __restrict__ F,
                                   unsigned short* lds, int ct, int tid) {
#pragma unroll
  for (int i = 0; i < 4; ++i) {
    const int n = i * 512 + tid;               // 16B-slot 0..2047
    const int j = n >> 5;                      // row 0..63
    const int m = (n & 31) ^ (j & 31);         // swizzled 16B k-chunk
    load_lds16(F + ((size_t)(ct * 64 + j) << 8) + m * 8,
               lds + (size_t)n * 8);
  }
}

}  // namespace

// ---------------- K0: prep (zero ns/out, scales, active-tile list) --------
__global__ __launch_bounds__(256) void k_prep(
    const int* __restrict__ labels, float* __restrict__ ns,
    float* __restrict__ out, int out_size, int* __restrict__ nact,
    ushort2* __restrict__ list, float* __restrict__ cscale) {
  const int tid = (int)threadIdx.x;
  const int b = (int)blockIdx.x;
  for (int i = b * 256 + tid; i < kM; i += 64 * 256) ns[i] = 0.f;
  if (b != 0) return;
  __shared__ int s_lab[kT];
  if (tid < kT) s_lab[tid] = labels[tid];
  if (tid == 0) *nact = 0;
  for (int i = tid; i < out_size; i += 256) out[i] = 0.f;
  __syncthreads();
  if (tid < kT) {
    int m = 0;
    for (int u = 0; u < kT; ++u) m += (s_lab[u] == s_lab[tid]) ? 1 : 0;
    cscale[tid] = 1.f / ((float)(m * kV - 1) * (float)kM);
  }
  for (int p = tid; p < kT * kT; p += 256) {
    const int ti = p >> 5, tj = p & 31;
    if (s_lab[ti] == s_lab[tj]) {
      int base = atomicAdd(nact, 16);
#pragma unroll
      for (int a = 0; a < 4; ++a)
#pragma unroll
        for (int bb = 0; bb < 4; ++bb) {
          ushort2 e;
          e.x = (unsigned short)(ti * 4 + a);  // bi 0..127
          e.y = (unsigned short)(tj * 4 + bb); // bj 0..127
          list[base + a * 4 + bb] = e;
        }
    }
  }
}

// ---------------- K1: gather (coalesced row staging) ----------------
__global__ __launch_bounds__(256) void k_gather(
    const float* __restrict__ feat, const int* __restrict__ binds,
    const int* __restrict__ sinds, unsigned short* __restrict__ FT) {
  const int b = (int)blockIdx.x;   // 0..7
  const int c = (int)blockIdx.y;   // 0..255
  __shared__ alignas(16) float row[kHW];
  __shared__ int s_match[kT + 1];
  if (threadIdx.x == 0) {
    int cnt = 0;
    for (int t = 0; t < kT; ++t)
      if (binds[t] == b) s_match[1 + cnt++] = t;
    s_match[0] = cnt;
  }
  __syncthreads();
  const int cnt = s_match[0];
  if (cnt == 0) return;
  const float4* src4 = (const float4*)(feat + ((size_t)b * kC + c) * kHW);
  for (int i = (int)threadIdx.x; i < kHW / 4; i += 256)
    ((float4*)row)[i] = src4[i];
  __syncthreads();
  unsigned short* dst = FT + (size_t)c * kM;
  for (int mi = 1; mi <= cnt; ++mi) {
    const int t = s_match[mi];
    const int p = sinds[t * kV + threadIdx.x];
    dst[t * kV + threadIdx.x] = f2bf(row[p]);
  }
}

// ---------------- K2: transpose + normalize ----------------
__global__ __launch_bounds__(256) void k_norm(
    const unsigned short* __restrict__ FT, unsigned short* __restrict__ F) {
  constexpr int PAD = 40;  // 32 vecs + 8 pad (80 B rows: breaks bank aliasing)
  const int v0 = (int)blockIdx.x * 32;
  __shared__ alignas(16) unsigned short tile[kC][PAD];
  __shared__ float part[8][32];
  __shared__ float s_inv[32];
  const int tid = (int)threadIdx.x;
  {
    const int p4 = tid & 3, cb = tid >> 2;  // 4x16B per 64B c-row
    for (int c = cb; c < kC; c += 64) {
      int4 d = *(const int4*)(FT + (size_t)c * kM + v0 + p4 * 8);
      *(int4*)&tile[c][p4 * 8] = d;
    }
  }
  __syncthreads();
  {
    const int v = tid & 31, oct = tid >> 5;
    float ss = 0.f;
    for (int c = oct * 32; c < oct * 32 + 32; ++c) {
      float x = bf2f(tile[c][v]);
      ss += x * x;
    }
    part[oct][v] = ss;
  }
  __syncthreads();
  if (tid < 32) {
    float ss = 0.f;
#pragma unroll
    for (int o = 0; o < 8; ++o) ss += part[o][tid];
    s_inv[tid] = 1.0f / fmaxf(sqrtf(ss), 1e-12f);
  }
  __syncthreads();
#pragma unroll
  for (int p = 0; p < 4; ++p) {
    const int chunk = p * 256 + tid;
    const int v = chunk >> 5, c0 = (chunk & 31) << 3;
    const float inv = s_inv[v];
    alignas(16) unsigned short o[8];
#pragma unroll
    for (int k = 0; k < 8; ++k) o[k] = f2bf(bf2f(tile[c0 + k][v]) * inv);
    *(int4*)(F + (size_t)(v0 + v) * kC + c0) = *(const int4*)o;
  }
}

// ---------------- K3: negative sweep -> ns[row] ----------------
// grid 512 x 512 threads: panel = bid&7 (1024 cols, XCD-pinned), rowblock
// rb = bid>>3 (128 rows). Waves 4(wr) x 2(wc), 32x32 out each, af[2][8]
// register-resident (LDS-sourced). DOUBLE-buffered B staging, T3-minimum
// order: barrier -> issue prefetch into other buffer -> compute current.
// The prefetch drains at the NEXT barrier (one compute-phase of latency
// hiding). LDS 66.6 KB -> 2 blocks/CU x 8 waves = 16 waves/CU.
__global__ __launch_bounds__(512, 4) void k_neg(
    const unsigned short* __restrict__ F, const int* __restrict__ labels,
    float* __restrict__ ns) {
  const int tid = (int)threadIdx.x;
  const int w = tid >> 6, lane = tid & 63, q = lane >> 4, l16 = lane & 15;
  const int wr = w >> 1, wc = w & 1;
  const int bid = (int)blockIdx.x;  // 0..511
  const int panel = bid & 7;        // 0..7 (XCD-pinned 1024-col panel)
  const int rb = bid >> 3;          // 0..63 (128-row block)
  const int row0 = rb * 128;
  __shared__ alignas(16) unsigned short Bt[2][64 * kC];  // 2 x 32 KB, swizzled
  __shared__ int s_lab[kT];
  __shared__ int s_tiles[16];
  __shared__ int s_nt;
  __shared__ float s_red[8][32];
  if (tid < kT) s_lab[tid] = labels[tid];
  __syncthreads();
  const int labr = s_lab[rb >> 1];
  if (tid == 0) {  // compacted negative-tile list (block-uniform skip)
    int n = 0;
    for (int ct = panel * 16; ct < panel * 16 + 16; ++ct)
      if (s_lab[ct >> 2] != labr) s_tiles[n++] = ct;
    s_nt = n;
  }
  __syncthreads();
  const int nt = s_nt;
  if (nt == 0) return;

  // --- A prologue: both 64-row halves staged at once (one barrier), then
  // each wave reads its af from the matching buffer. Sourcing af from
  // soon-overwritten LDS keeps it register-resident (proven: VGPR=88, r6).
  stage_tile8(F, Bt[0], rb * 2, tid);      // rows row0 .. row0+63
  stage_tile8(F, Bt[1], rb * 2 + 1, tid);  // rows row0+64 .. row0+127
  __syncthreads();
  short8 af[2][8];
  {
    const unsigned short* abuf = Bt[wr >> 1];  // wr 0,1 -> half0; 2,3 -> half1
    const int wl = wr & 1;                     // local 64-row half
#pragma unroll
    for (int rg = 0; rg < 2; ++rg) {
      const int ja = wl * 32 + rg * 16 + l16;  // local row 0..63
      const unsigned short* arow = abuf + ja * kC;
#pragma unroll
      for (int ks = 0; ks < 8; ++ks)
        af[rg][ks] =
            *(const short8*)(arow + (((ks * 4 + q) ^ (ja & 31)) << 3));
    }
  }
  __syncthreads();  // all af reads done before Bt is overwritten

  // B columns for this wave: jb0 = wc*32 + l16, jb1 = jb0 + 16.
  // (jb0 & 31) == l16, (jb1 & 31) == l16|16  =>  bofs1 = bofs0 ^ 128.
  const int jrow = wc * 32 + l16;
  int bofs[8];
#pragma unroll
  for (int ks = 0; ks < 8; ++ks) bofs[ks] = ((ks * 4 + q) ^ l16) << 3;

  // Prologue prefetch of tile 0 (issued after the af barrier; drained at
  // the first loop barrier — the only unhidden stage latency).
  stage_tile8(F, Bt[0], s_tiles[0], tid);

  float sacc[2][4] = {};
  for (int it = 0; it < nt; ++it) {
    __syncthreads();  // drains stage(tile it); prev-tile readers are done
    if (it + 1 < nt) stage_tile8(F, Bt[(it + 1) & 1], s_tiles[it + 1], tid);
    const unsigned short* bc0 = Bt[it & 1] + jrow * kC;
    const unsigned short* bc1 = bc0 + 16 * kC;
    f32x4 a00 = {0.f, 0.f, 0.f, 0.f}, a01 = a00, a10 = a00, a11 = a00;
#pragma unroll
    for (int ks = 0; ks < 8; ++ks) {
      short8 b0 = *(const short8*)(bc0 + bofs[ks]);
      short8 b1 = *(const short8*)(bc1 + (bofs[ks] ^ 128));
      a00 = __builtin_amdgcn_mfma_f32_16x16x32_bf16(af[0][ks], b0, a00, 0, 0, 0);
      a01 = __builtin_amdgcn_mfma_f32_16x16x32_bf16(af[0][ks], b1, a01, 0, 0, 0);
      a10 = __builtin_amdgcn_mfma_f32_16x16x32_bf16(af[1][ks], b0, a10, 0, 0, 0);
      a11 = __builtin_amdgcn_mfma_f32_16x16x32_bf16(af[1][ks], b1, a11, 0, 0, 0);
    }
#pragma unroll
    for (int r = 0; r < 4; ++r) {
      sacc[0][r] += exp_2am2(a00[r]) + exp_2am2(a01[r]);
      sacc[1][r] += exp_2am2(a10[r]) + exp_2am2(a11[r]);
    }
  }

  // Row reduction: sum over the wave's 16 columns (l16 lanes), then across
  // the two wc-waves sharing each row, then one atomicAdd per row.
#pragma unroll
  for (int rg = 0; rg < 2; ++rg)
#pragma unroll
    for (int r = 0; r < 4; ++r) {
      float v = sacc[rg][r];
      v += __shfl_xor(v, 1, 64);
      v += __shfl_xor(v, 2, 64);
      v += __shfl_xor(v, 4, 64);
      v += __shfl_xor(v, 8, 64);
      if (l16 == 0) s_red[w][rg * 16 + q * 4 + r] = v;
    }
  __syncthreads();
  if (tid < 128) {
    const int rr = tid >> 5, e = tid & 31;  // row = row0 + rr*32 + e
    float v = s_red[rr * 2][e] + s_red[rr * 2 + 1][e];
    atomicAdd(&ns[row0 + tid], v);
  }
}

// ---------------- K4: positive sweep -> loss (list-driven) ----------------
__global__ __launch_bounds__(256, 3) void k_pos(
    const unsigned short* __restrict__ F, const float* __restrict__ ns,
    const int* __restrict__ nact, const ushort2* __restrict__ list,
    const float* __restrict__ cscale, float* __restrict__ out) {
  const int tid = (int)threadIdx.x;
  const int w = tid >> 6, lane = tid & 63, q = lane >> 4, l16 = lane & 15;
  const int wr = w >> 1, wc = w & 1;
  __shared__ alignas(16) unsigned short Bt[64 * kC];  // 32 KB, swizzled
  __shared__ float s_pos[4];
  const int n = *nact;

  const int jb0 = wc * 32 + l16, jb1 = wc * 32 + 16 + l16;
  int bofs0[8], bofs1[8];
#pragma unroll
  for (int ks = 0; ks < 8; ++ks) {
    bofs0[ks] = (((ks * 4 + q) ^ (jb0 & 31)) << 3);
    bofs1[ks] = (((ks * 4 + q) ^ (jb1 & 31)) << 3);
  }
  const unsigned short* bc0 = (const unsigned short*)Bt + jb0 * kC;
  const unsigned short* bc1 = (const unsigned short*)Bt + jb1 * kC;

  float pos = 0.f;
  for (int idx = (int)blockIdx.x; idx < n; idx += (int)gridDim.x) {
    const ushort2 e = list[idx];
    const int bi = e.x, bj = e.y;
    stage_tile4(F, Bt, bj, tid);  // async; drained at the barrier below

    short8 af[2][8];
#pragma unroll
    for (int rg = 0; rg < 2; ++rg) {
      const int row = bi * 64 + wr * 32 + rg * 16 + l16;
#pragma unroll
      for (int ks = 0; ks < 8; ++ks)
        af[rg][ks] = *(const short8*)((const short*)F + (size_t)row * kC +
                                      ks * 32 + q * 8);
    }
    float nsv[2][4];
#pragma unroll
    for (int rg = 0; rg < 2; ++rg)
#pragma unroll
      for (int r = 0; r < 4; ++r)
        nsv[rg][r] = ns[bi * 64 + wr * 32 + rg * 16 + q * 4 + r];
    const float scale = cscale[bi >> 2];

    __syncthreads();  // B tile staged (+ af/nsv drained by vmcnt)

    f32x4 a00 = {0.f, 0.f, 0.f, 0.f}, a01 = a00, a10 = a00, a11 = a00;
#pragma unroll
    for (int ks = 0; ks < 8; ++ks) {
      short8 b0 = *(const short8*)(bc0 + bofs0[ks]);
      short8 b1 = *(const short8*)(bc1 + bofs1[ks]);
      a00 = __builtin_amdgcn_mfma_f32_16x16x32_bf16(af[0][ks], b0, a00, 0, 0, 0);
      a01 = __builtin_amdgcn_mfma_f32_16x16x32_bf16(af[0][ks], b1, a01, 0, 0, 0);
      a10 = __builtin_amdgcn_mfma_f32_16x16x32_bf16(af[1][ks], b0, a10, 0, 0, 0);
      a11 = __builtin_amdgcn_mfma_f32_16x16x32_bf16(af[1][ks], b1, a11, 0, 0, 0);
    }

    float tpos = 0.f;
#pragma unroll
    for (int rg = 0; rg < 2; ++rg)
#pragma unroll
      for (int cg = 0; cg < 2; ++cg) {
        const f32x4 acc = (rg == 0) ? (cg == 0 ? a00 : a01)
                                    : (cg == 0 ? a10 : a11);
        const int jc = bj * 64 + wc * 32 + cg * 16 + l16;
#pragma unroll
        for (int r = 0; r < 4; ++r) {
          const int i = bi * 64 + wr * 32 + rg * 16 + q * 4 + r;
          if (i != jc) {
            float d = fmaf(acc[r], 2.f, -2.f);
            tpos += d - __logf(__expf(d) + nsv[rg][r]);
          }
        }
      }
    pos += scale * tpos;
    __syncthreads();  // all waves done reading Bt before next stage
  }

#pragma unroll
  for (int m = 1; m < 64; m <<= 1) pos += __shfl_xor(pos, m, 64);
  if (lane == 0) s_pos[w] = pos;
  __syncthreads();
  if (tid == 0)
    atomicAdd(out, -(s_pos[0] + s_pos[1] + s_pos[2] + s_pos[3]));
}

extern "C" void kernel_launch(void* const* d_in, const int* in_sizes, int n_in,
                              void* d_out, int out_size, void* d_ws,
                              size_t ws_size, hipStream_t stream) {
  const float* feat = (const float*)d_in[0];
  const int* binds = (const int*)d_in[1];
  const int* sinds = (const int*)d_in[2];
  const int* labels = (const int*)d_in[3];
  float* out = (float*)d_out;
  unsigned short* FT = (unsigned short*)d_ws;            // 4 MB  [256][8192]
  unsigned short* F = FT + (size_t)kC * kM;              // 4 MB  [8192][256]
  float* ns = (float*)(F + (size_t)kM * kC);             // 32 KB [8192]
  int* nact = (int*)(ns + kM);                           // 4 B (+pad)
  float* cscale = (float*)(nact + 8);                    // 128 B [32]
  ushort2* list = (ushort2*)(cscale + 32);               // 64 KB [16384]

  k_prep<<<64, 256, 0, stream>>>(labels, ns, out, out_size, nact, list, cscale);
  k_gather<<<dim3(8, kC), 256, 0, stream>>>(feat, binds, sinds, FT);
  k_norm<<<kM / 32, 256, 0, stream>>>(FT, F);
  k_neg<<<dim3(512), 512, 0, stream>>>(F, labels, ns);
  k_pos<<<768, 256, 0, stream>>>(F, ns, nact, list, cscale, out);
}

// Round 8
// 179.530 us; speedup vs baseline: 1.0453x; 1.0453x over previous
//
#include <hip/hip_runtime.h>
#include <hip/hip_bf16.h>

// DenseContrastiveLossV2 on MI355X — round 9.
// Round-8 verdict: the LDS staging+barrier structure itself is the wall
// (4 schedule variants all ~52us; VGPR=64 shows the allocator fighting
// operand residency to chase occupancy hints). F is 4 MB = L2-resident,
// a B-tile is 16 KB = L1-resident -> LDS is pure overhead here.
// New k_neg: ZERO LDS. k_norm emits F2 in MFMA *fragment* layout
// ([g16][ks][lane][8e]) so A/B fragments are single coalesced dwordx4
// loads. 64-row waves keep af[4][8] (128 VGPR) resident via
// amdgpu_waves_per_eu(2,2) (kills the remat incentive); 8 waves/block
// share a 512-col panel -> each 16 KB B-tile is read 8x from L1, 1x from
// L2. Raw s_barrier (safe: no LDS, uniform 16-ct flow w/ masked accum)
// keeps waves converged for L1 hits. MFMA floor ~16.6us.
// K0 k_prep   : zero ns/out, cscale, pos-pair list at (r32,c32) granularity.
// K1 k_gather : unchanged.
// K2 k_norm   : transpose+normalize -> F2 fragment layout.
// K3 k_neg    : LDS-free panel sweep, masked exp accumulation.
// K4 k_pos    : LDS-free list consumer.

namespace {

constexpr int kC = 256;
constexpr int kHW = 96 * 96;   // 9216
constexpr int kT = 32;
constexpr int kV = 256;
constexpr int kM = kT * kV;    // 8192

typedef __attribute__((ext_vector_type(8))) short short8;  // 8 bf16
typedef __attribute__((ext_vector_type(4))) float f32x4;

__device__ inline unsigned short f2bf(float x) {
  __hip_bfloat16 h = __float2bfloat16(x);
  return __builtin_bit_cast(unsigned short, h);
}
__device__ inline float bf2f(unsigned short u) {
  unsigned int v = ((unsigned int)u) << 16;
  return __builtin_bit_cast(float, v);
}
// exp(2a-2) = exp2(a*2log2e - 2log2e); one fma + native v_exp_f32.
__device__ inline float exp_2am2(float a) {
  return exp2f(fmaf(a, 2.8853900818f, -2.8853900818f));
}

// F2 fragment layout: for 16-vec group g, k-group ks (k = ks*32+q*8+e),
// lane (q*16+l16) stores elems e=0..7 of F[v=g*16+l16][c=ks*32+q*8+e].
// Slot offset in shorts: ((g*8+ks)*64 + q*16 + l16) * 8  ==  ((g*8+ks)<<9)
// + ((q*16+l16)<<3). One MFMA A- or B-fragment = one 16B coalesced load.

}  // namespace

// ---------------- K0: prep (zero ns/out, scales, pos-pair list) -----------
__global__ __launch_bounds__(256) void k_prep(
    const int* __restrict__ labels, float* __restrict__ ns,
    float* __restrict__ out, int out_size, int* __restrict__ nact,
    ushort2* __restrict__ list, float* __restrict__ cscale) {
  const int tid = (int)threadIdx.x;
  const int b = (int)blockIdx.x;
  for (int i = b * 256 + tid; i < kM; i += 64 * 256) ns[i] = 0.f;
  if (b != 0) return;
  __shared__ int s_lab[kT];
  if (tid < kT) s_lab[tid] = labels[tid];
  if (tid == 0) *nact = 0;
  for (int i = tid; i < out_size; i += 256) out[i] = 0.f;
  __syncthreads();
  if (tid < kT) {
    int m = 0;
    for (int u = 0; u < kT; ++u) m += (s_lab[u] == s_lab[tid]) ? 1 : 0;
    cscale[tid] = 1.f / ((float)(m * kV - 1) * (float)kM);
  }
  for (int p = tid; p < kT * kT; p += 256) {
    const int ti = p >> 5, tj = p & 31;
    if (s_lab[ti] == s_lab[tj]) {
      int base = atomicAdd(nact, 64);  // 8x8 (r32,c32) sub-tiles per t-pair
#pragma unroll
      for (int a = 0; a < 8; ++a)
#pragma unroll
        for (int bb = 0; bb < 8; ++bb) {
          ushort2 e;
          e.x = (unsigned short)(ti * 8 + a);  // r32 0..255
          e.y = (unsigned short)(tj * 8 + bb); // c32 0..255
          list[base + a * 8 + bb] = e;
        }
    }
  }
}

// ---------------- K1: gather (coalesced row staging) ----------------
__global__ __launch_bounds__(256) void k_gather(
    const float* __restrict__ feat, const int* __restrict__ binds,
    const int* __restrict__ sinds, unsigned short* __restrict__ FT) {
  const int b = (int)blockIdx.x;   // 0..7
  const int c = (int)blockIdx.y;   // 0..255
  __shared__ alignas(16) float row[kHW];
  __shared__ int s_match[kT + 1];
  if (threadIdx.x == 0) {
    int cnt = 0;
    for (int t = 0; t < kT; ++t)
      if (binds[t] == b) s_match[1 + cnt++] = t;
    s_match[0] = cnt;
  }
  __syncthreads();
  const int cnt = s_match[0];
  if (cnt == 0) return;
  const float4* src4 = (const float4*)(feat + ((size_t)b * kC + c) * kHW);
  for (int i = (int)threadIdx.x; i < kHW / 4; i += 256)
    ((float4*)row)[i] = src4[i];
  __syncthreads();
  unsigned short* dst = FT + (size_t)c * kM;
  for (int mi = 1; mi <= cnt; ++mi) {
    const int t = s_match[mi];
    const int p = sinds[t * kV + threadIdx.x];
    dst[t * kV + threadIdx.x] = f2bf(row[p]);
  }
}

// ---------------- K2: transpose + normalize -> F2 fragment layout ---------
__global__ __launch_bounds__(256) void k_norm(
    const unsigned short* __restrict__ FT, unsigned short* __restrict__ F2) {
  constexpr int PAD = 40;  // 32 vecs + 8 pad (80 B rows: breaks bank aliasing)
  const int v0 = (int)blockIdx.x * 32;
  __shared__ alignas(16) unsigned short tile[kC][PAD];
  __shared__ float part[8][32];
  __shared__ float s_inv[32];
  const int tid = (int)threadIdx.x;
  {
    const int p4 = tid & 3, cb = tid >> 2;  // 4x16B per 64B c-row
    for (int c = cb; c < kC; c += 64) {
      int4 d = *(const int4*)(FT + (size_t)c * kM + v0 + p4 * 8);
      *(int4*)&tile[c][p4 * 8] = d;
    }
  }
  __syncthreads();
  {
    const int v = tid & 31, oct = tid >> 5;
    float ss = 0.f;
    for (int c = oct * 32; c < oct * 32 + 32; ++c) {
      float x = bf2f(tile[c][v]);
      ss += x * x;
    }
    part[oct][v] = ss;
  }
  __syncthreads();
  if (tid < 32) {
    float ss = 0.f;
#pragma unroll
    for (int o = 0; o < 8; ++o) ss += part[o][tid];
    s_inv[tid] = 1.0f / fmaxf(sqrtf(ss), 1e-12f);
  }
  __syncthreads();
  // Write fragment layout: slot -> (gl, ks, q, l16); consecutive tid ->
  // consecutive 16B slots (fully coalesced per wave).
#pragma unroll
  for (int p = 0; p < 4; ++p) {
    const int slot = p * 256 + tid;  // 0..1023
    const int l16s = slot & 15;
    const int qs = (slot >> 4) & 3;
    const int kss = (slot >> 6) & 7;
    const int gl = slot >> 9;  // 0..1
    const int vloc = gl * 16 + l16s;
    const int c0 = kss * 32 + qs * 8;
    const float inv = s_inv[vloc];
    alignas(16) unsigned short o[8];
#pragma unroll
    for (int k = 0; k < 8; ++k) o[k] = f2bf(bf2f(tile[c0 + k][vloc]) * inv);
    *(int4*)(F2 + ((size_t)(((v0 >> 4) + gl) * 8 + kss) << 9) +
             ((qs * 16 + l16s) << 3)) = *(const int4*)o;
  }
}

// ---------------- K3: negative sweep -> ns[row] (LDS-free) ----------------
// 256 blocks x 512 thr (1/CU). panel = bid&15 (512 cols; XCD-pinned via
// dispatch round-robin: XCD x serves panels x, x+8 -> 1 MB B in its L2).
// rb = bid>>4 (512 rows). Wave w owns rows rb*512 + w*64 (64 rows) and
// sweeps all 16 col-tiles (32 cols each) of the panel; pos tiles are
// computed but masked out of the accumulation (uniform flow -> raw
// s_barrier is safe and keeps the 8 waves L1-converged).
__global__ __attribute__((amdgpu_flat_work_group_size(512, 512),
                          amdgpu_waves_per_eu(2, 2))) void k_neg(
    const unsigned short* __restrict__ F2, const int* __restrict__ labels,
    float* __restrict__ ns) {
  const int tid = (int)threadIdx.x;
  const int w = tid >> 6, lane = tid & 63, q = lane >> 4, l16 = lane & 15;
  const int bid = (int)blockIdx.x;  // 0..255
  const int panel = bid & 15;       // 512-col panel
  const int rb = bid >> 4;          // 0..15 (512-row block)
  const int rowbase = rb * 512 + w * 64;
  const int labr = labels[rowbase >> 8];
  const bool use0 = (labels[panel * 2] != labr);
  const bool use1 = (labels[panel * 2 + 1] != labr);

  const unsigned short* lanep = F2 + ((q * 16 + l16) << 3);

  // A fragments: 64 rows x 256 k = 32 frags = 128 VGPR, loaded once.
  short8 af[4][8];
  const int ga = rowbase >> 4;
#pragma unroll
  for (int rg = 0; rg < 4; ++rg)
#pragma unroll
    for (int ks = 0; ks < 8; ++ks)
      af[rg][ks] =
          *(const short8*)(lanep + ((size_t)((ga + rg) * 8 + ks) << 9));

  float sacc[4][4] = {};
  for (int ct = 0; ct < 16; ++ct) {
    const bool use = (ct < 8) ? use0 : use1;
    const int gc = panel * 32 + ct * 2;
    // cg=0 fragments (8 x dwordx4, L1-broadcast across the 8 waves)
    short8 bf[8];
#pragma unroll
    for (int ks = 0; ks < 8; ++ks)
      bf[ks] = *(const short8*)(lanep + ((size_t)(gc * 8 + ks) << 9));
    asm volatile("s_barrier" ::: "memory");  // converge; no LDS -> raw safe
    f32x4 acc0[4];
#pragma unroll
    for (int rg = 0; rg < 4; ++rg) acc0[rg] = (f32x4){0.f, 0.f, 0.f, 0.f};
#pragma unroll
    for (int ks = 0; ks < 8; ++ks)
#pragma unroll
      for (int rg = 0; rg < 4; ++rg)
        acc0[rg] = __builtin_amdgcn_mfma_f32_16x16x32_bf16(af[rg][ks], bf[ks],
                                                           acc0[rg], 0, 0, 0);
    // cg=1 fragments (reuse bf regs; other wave's MFMA covers the latency)
#pragma unroll
    for (int ks = 0; ks < 8; ++ks)
      bf[ks] =
          *(const short8*)(lanep + ((size_t)((gc + 1) * 8 + ks) << 9));
    f32x4 acc1[4];
#pragma unroll
    for (int rg = 0; rg < 4; ++rg) acc1[rg] = (f32x4){0.f, 0.f, 0.f, 0.f};
#pragma unroll
    for (int ks = 0; ks < 8; ++ks)
#pragma unroll
      for (int rg = 0; rg < 4; ++rg)
        acc1[rg] = __builtin_amdgcn_mfma_f32_16x16x32_bf16(af[rg][ks], bf[ks],
                                                           acc1[rg], 0, 0, 0);
    if (use) {
#pragma unroll
      for (int rg = 0; rg < 4; ++rg)
#pragma unroll
        for (int r = 0; r < 4; ++r)
          sacc[rg][r] += exp_2am2(acc0[rg][r]) + exp_2am2(acc1[rg][r]);
    }
  }

  // Row-sum over the 16 l16 lanes (32 cols folded into sacc already),
  // then one atomicAdd per row (16 panel contenders per ns entry).
#pragma unroll
  for (int rg = 0; rg < 4; ++rg)
#pragma unroll
    for (int r = 0; r < 4; ++r) {
      float v = sacc[rg][r];
      v += __shfl_xor(v, 1, 64);
      v += __shfl_xor(v, 2, 64);
      v += __shfl_xor(v, 4, 64);
      v += __shfl_xor(v, 8, 64);
      if (l16 == 0) atomicAdd(&ns[rowbase + rg * 16 + q * 4 + r], v);
    }
}

// ---------------- K4: positive sweep -> loss (LDS-free, list-driven) ------
__global__ __launch_bounds__(256, 2) void k_pos(
    const unsigned short* __restrict__ F2, const float* __restrict__ ns,
    const int* __restrict__ nact, const ushort2* __restrict__ list,
    const float* __restrict__ cscale, float* __restrict__ out) {
  const int tid = (int)threadIdx.x;
  const int w = tid >> 6, lane = tid & 63, q = lane >> 4, l16 = lane & 15;
  __shared__ float s_pos[4];
  const int n = *nact;
  const unsigned short* lanep = F2 + ((q * 16 + l16) << 3);

  float pos = 0.f;
  for (int idx = (int)blockIdx.x * 4 + w; idx < n;
       idx += (int)gridDim.x * 4) {
    const ushort2 e = list[idx];
    const int r32 = e.x, c32 = e.y;
    const int ga = r32 * 2, gb = c32 * 2;
    short8 af[2][8], bf[2][8];
#pragma unroll
    for (int rg = 0; rg < 2; ++rg)
#pragma unroll
      for (int ks = 0; ks < 8; ++ks) {
        af[rg][ks] =
            *(const short8*)(lanep + ((size_t)((ga + rg) * 8 + ks) << 9));
        bf[rg][ks] =
            *(const short8*)(lanep + ((size_t)((gb + rg) * 8 + ks) << 9));
      }
    float nsv[2][4];
#pragma unroll
    for (int rg = 0; rg < 2; ++rg)
#pragma unroll
      for (int r = 0; r < 4; ++r)
        nsv[rg][r] = ns[r32 * 32 + rg * 16 + q * 4 + r];
    const float scale = cscale[r32 >> 3];

    f32x4 a00 = {0.f, 0.f, 0.f, 0.f}, a01 = a00, a10 = a00, a11 = a00;
#pragma unroll
    for (int ks = 0; ks < 8; ++ks) {
      a00 = __builtin_amdgcn_mfma_f32_16x16x32_bf16(af[0][ks], bf[0][ks], a00,
                                                    0, 0, 0);
      a01 = __builtin_amdgcn_mfma_f32_16x16x32_bf16(af[0][ks], bf[1][ks], a01,
                                                    0, 0, 0);
      a10 = __builtin_amdgcn_mfma_f32_16x16x32_bf16(af[1][ks], bf[0][ks], a10,
                                                    0, 0, 0);
      a11 = __builtin_amdgcn_mfma_f32_16x16x32_bf16(af[1][ks], bf[1][ks], a11,
                                                    0, 0, 0);
    }
    float tpos = 0.f;
#pragma unroll
    for (int rg = 0; rg < 2; ++rg)
#pragma unroll
      for (int cg = 0; cg < 2; ++cg) {
        const f32x4 acc =
            (rg == 0) ? (cg == 0 ? a00 : a01) : (cg == 0 ? a10 : a11);
        const int jc = c32 * 32 + cg * 16 + l16;
#pragma unroll
        for (int r = 0; r < 4; ++r) {
          const int i = r32 * 32 + rg * 16 + q * 4 + r;
          if (i != jc) {
            float d = fmaf(acc[r], 2.f, -2.f);
            tpos += d - __logf(exp_2am2(acc[r]) + nsv[rg][r]);
          }
        }
      }
    pos += scale * tpos;
  }

#pragma unroll
  for (int m = 1; m < 64; m <<= 1) pos += __shfl_xor(pos, m, 64);
  if (lane == 0) s_pos[w] = pos;
  __syncthreads();
  if (tid == 0)
    atomicAdd(out, -(s_pos[0] + s_pos[1] + s_pos[2] + s_pos[3]));
}

extern "C" void kernel_launch(void* const* d_in, const int* in_sizes, int n_in,
                              void* d_out, int out_size, void* d_ws,
                              size_t ws_size, hipStream_t stream) {
  const float* feat = (const float*)d_in[0];
  const int* binds = (const int*)d_in[1];
  const int* sinds = (const int*)d_in[2];
  const int* labels = (const int*)d_in[3];
  float* out = (float*)d_out;
  unsigned short* FT = (unsigned short*)d_ws;            // 4 MB  [256][8192]
  unsigned short* F2 = FT + (size_t)kC * kM;             // 4 MB  fragment fmt
  float* ns = (float*)(F2 + (size_t)kM * kC);            // 32 KB [8192]
  int* nact = (int*)(ns + kM);                           // 4 B (+pad)
  float* cscale = (float*)(nact + 8);                    // 128 B [32]
  ushort2* list = (ushort2*)(cscale + 32);               // <=256 KB [65536]

  k_prep<<<64, 256, 0, stream>>>(labels, ns, out, out_size, nact, list, cscale);
  k_gather<<<dim3(8, kC), 256, 0, stream>>>(feat, binds, sinds, FT);
  k_norm<<<kM / 32, 256, 0, stream>>>(FT, F2);
  k_neg<<<256, 512, 0, stream>>>(F2, labels, ns);
  k_pos<<<512, 256, 0, stream>>>(F2, ns, nact, list, cscale, out);
}

// Round 9
// 175.788 us; speedup vs baseline: 1.0676x; 1.0213x over previous
//
#include <hip/hip_runtime.h>
#include <hip/hip_bf16.h>

// DenseContrastiveLossV2 on MI355X — round 10.
// Round-9 post-mortem: LDS-free k_neg = 45.8us, VGPR=100 -> the allocator
// AGAIN sank the af[4][8] loads into the ct loop (4th failed residency
// attempt via pressure tuning). Fix: structural, not heuristic — the inner
// MFMA is inline asm with the A-operand in an "a" (AGPR) constraint. The
// compiler must copy af to AGPRs ONCE (128 v_accvgpr_write before the
// loop); AGPRs can't be reloaded from global memory, arch-VGPR pressure
// drops to ~90, grid is 1 block/CU so occupancy is irrelevant.
// Floors: MFMA 16.6us/CU; L1 B-reads at rg=4 resident = 13.6us. Target ~20.
// K0 k_prep   : zero ns/out, cscale, pos-pair list. (unchanged)
// K1 k_gather : unchanged.
// K2 k_norm   : transpose+normalize -> F2 fragment layout. (unchanged)
// K3 k_neg    : LDS-free panel sweep; af in AGPRs via asm MFMA.
// K4 k_pos    : unchanged.

namespace {

constexpr int kC = 256;
constexpr int kHW = 96 * 96;   // 9216
constexpr int kT = 32;
constexpr int kV = 256;
constexpr int kM = kT * kV;    // 8192

typedef __attribute__((ext_vector_type(8))) short short8;  // 8 bf16
typedef __attribute__((ext_vector_type(4))) float f32x4;

__device__ inline unsigned short f2bf(float x) {
  __hip_bfloat16 h = __float2bfloat16(x);
  return __builtin_bit_cast(unsigned short, h);
}
__device__ inline float bf2f(unsigned short u) {
  unsigned int v = ((unsigned int)u) << 16;
  return __builtin_bit_cast(float, v);
}
// exp(2a-2) = exp2(a*2log2e - 2log2e); one fma + native v_exp_f32.
__device__ inline float exp_2am2(float a) {
  return exp2f(fmaf(a, 2.8853900818f, -2.8853900818f));
}

// MFMA with the A-fragment pinned in AGPRs ("a" constraint): the copy to
// AGPR happens once at first use; the allocator cannot "remat" AGPRs from
// memory, so the 128-reg A-tile stays resident across the ct loop.
__device__ inline void mfma_agpr(f32x4& acc, const short8& a,
                                 const short8& b) {
  asm("v_mfma_f32_16x16x32_bf16 %0, %1, %2, %0"
      : "+v"(acc)
      : "a"(a), "v"(b));
}

// F2 fragment layout: for 16-vec group g, k-group ks (k = ks*32+q*8+e),
// lane (q*16+l16) stores elems e=0..7 of F[v=g*16+l16][c=ks*32+q*8+e].
// Slot offset in shorts: ((g*8+ks)<<9) + ((q*16+l16)<<3).
// One MFMA A- or B-fragment = one 16B coalesced load.

}  // namespace

// ---------------- K0: prep (zero ns/out, scales, pos-pair list) -----------
__global__ __launch_bounds__(256) void k_prep(
    const int* __restrict__ labels, float* __restrict__ ns,
    float* __restrict__ out, int out_size, int* __restrict__ nact,
    ushort2* __restrict__ list, float* __restrict__ cscale) {
  const int tid = (int)threadIdx.x;
  const int b = (int)blockIdx.x;
  for (int i = b * 256 + tid; i < kM; i += 64 * 256) ns[i] = 0.f;
  if (b != 0) return;
  __shared__ int s_lab[kT];
  if (tid < kT) s_lab[tid] = labels[tid];
  if (tid == 0) *nact = 0;
  for (int i = tid; i < out_size; i += 256) out[i] = 0.f;
  __syncthreads();
  if (tid < kT) {
    int m = 0;
    for (int u = 0; u < kT; ++u) m += (s_lab[u] == s_lab[tid]) ? 1 : 0;
    cscale[tid] = 1.f / ((float)(m * kV - 1) * (float)kM);
  }
  for (int p = tid; p < kT * kT; p += 256) {
    const int ti = p >> 5, tj = p & 31;
    if (s_lab[ti] == s_lab[tj]) {
      int base = atomicAdd(nact, 64);  // 8x8 (r32,c32) sub-tiles per t-pair
#pragma unroll
      for (int a = 0; a < 8; ++a)
#pragma unroll
        for (int bb = 0; bb < 8; ++bb) {
          ushort2 e;
          e.x = (unsigned short)(ti * 8 + a);  // r32 0..255
          e.y = (unsigned short)(tj * 8 + bb); // c32 0..255
          list[base + a * 8 + bb] = e;
        }
    }
  }
}

// ---------------- K1: gather (coalesced row staging) ----------------
__global__ __launch_bounds__(256) void k_gather(
    const float* __restrict__ feat, const int* __restrict__ binds,
    const int* __restrict__ sinds, unsigned short* __restrict__ FT) {
  const int b = (int)blockIdx.x;   // 0..7
  const int c = (int)blockIdx.y;   // 0..255
  __shared__ alignas(16) float row[kHW];
  __shared__ int s_match[kT + 1];
  if (threadIdx.x == 0) {
    int cnt = 0;
    for (int t = 0; t < kT; ++t)
      if (binds[t] == b) s_match[1 + cnt++] = t;
    s_match[0] = cnt;
  }
  __syncthreads();
  const int cnt = s_match[0];
  if (cnt == 0) return;
  const float4* src4 = (const float4*)(feat + ((size_t)b * kC + c) * kHW);
  for (int i = (int)threadIdx.x; i < kHW / 4; i += 256)
    ((float4*)row)[i] = src4[i];
  __syncthreads();
  unsigned short* dst = FT + (size_t)c * kM;
  for (int mi = 1; mi <= cnt; ++mi) {
    const int t = s_match[mi];
    const int p = sinds[t * kV + threadIdx.x];
    dst[t * kV + threadIdx.x] = f2bf(row[p]);
  }
}

// ---------------- K2: transpose + normalize -> F2 fragment layout ---------
__global__ __launch_bounds__(256) void k_norm(
    const unsigned short* __restrict__ FT, unsigned short* __restrict__ F2) {
  constexpr int PAD = 40;  // 32 vecs + 8 pad (80 B rows: breaks bank aliasing)
  const int v0 = (int)blockIdx.x * 32;
  __shared__ alignas(16) unsigned short tile[kC][PAD];
  __shared__ float part[8][32];
  __shared__ float s_inv[32];
  const int tid = (int)threadIdx.x;
  {
    const int p4 = tid & 3, cb = tid >> 2;  // 4x16B per 64B c-row
    for (int c = cb; c < kC; c += 64) {
      int4 d = *(const int4*)(FT + (size_t)c * kM + v0 + p4 * 8);
      *(int4*)&tile[c][p4 * 8] = d;
    }
  }
  __syncthreads();
  {
    const int v = tid & 31, oct = tid >> 5;
    float ss = 0.f;
    for (int c = oct * 32; c < oct * 32 + 32; ++c) {
      float x = bf2f(tile[c][v]);
      ss += x * x;
    }
    part[oct][v] = ss;
  }
  __syncthreads();
  if (tid < 32) {
    float ss = 0.f;
#pragma unroll
    for (int o = 0; o < 8; ++o) ss += part[o][tid];
    s_inv[tid] = 1.0f / fmaxf(sqrtf(ss), 1e-12f);
  }
  __syncthreads();
  // Write fragment layout: slot -> (gl, ks, q, l16); consecutive tid ->
  // consecutive 16B slots (fully coalesced per wave).
#pragma unroll
  for (int p = 0; p < 4; ++p) {
    const int slot = p * 256 + tid;  // 0..1023
    const int l16s = slot & 15;
    const int qs = (slot >> 4) & 3;
    const int kss = (slot >> 6) & 7;
    const int gl = slot >> 9;  // 0..1
    const int vloc = gl * 16 + l16s;
    const int c0 = kss * 32 + qs * 8;
    const float inv = s_inv[vloc];
    alignas(16) unsigned short o[8];
#pragma unroll
    for (int k = 0; k < 8; ++k) o[k] = f2bf(bf2f(tile[c0 + k][vloc]) * inv);
    *(int4*)(F2 + ((size_t)(((v0 >> 4) + gl) * 8 + kss) << 9) +
             ((qs * 16 + l16s) << 3)) = *(const int4*)o;
  }
}

// ---------------- K3: negative sweep -> ns[row] (LDS-free, AGPR A) --------
// 256 blocks x 512 thr (1/CU). panel = bid&15 (512 cols; XCD x serves
// panels x, x+8 -> 512 KB B in its L2). rb = bid>>4 (512 rows). Wave w
// owns rows rb*512 + w*64 and sweeps the panel's 16 col-tiles (32 cols);
// pos tiles computed but masked (uniform flow -> raw s_barrier safe,
// keeps the 8 waves L1-converged).
__global__ __attribute__((amdgpu_flat_work_group_size(512, 512))) void k_neg(
    const unsigned short* __restrict__ F2, const int* __restrict__ labels,
    float* __restrict__ ns) {
  const int tid = (int)threadIdx.x;
  const int w = tid >> 6, lane = tid & 63, q = lane >> 4, l16 = lane & 15;
  const int bid = (int)blockIdx.x;  // 0..255
  const int panel = bid & 15;       // 512-col panel
  const int rb = bid >> 4;          // 0..15 (512-row block)
  const int rowbase = rb * 512 + w * 64;
  const int labr = labels[rowbase >> 8];
  const bool use0 = (labels[panel * 2] != labr);
  const bool use1 = (labels[panel * 2 + 1] != labr);

  const unsigned short* lanep = F2 + ((q * 16 + l16) << 3);

  // A fragments: 64 rows x 256 k = 32 frags. Loaded once; consumed through
  // the "a"-constraint MFMA => copied to 128 AGPRs, resident by construction.
  short8 af[4][8];
  const int ga = rowbase >> 4;
#pragma unroll
  for (int rg = 0; rg < 4; ++rg)
#pragma unroll
    for (int ks = 0; ks < 8; ++ks)
      af[rg][ks] =
          *(const short8*)(lanep + ((size_t)((ga + rg) * 8 + ks) << 9));

  float sacc[4][4] = {};
  for (int ct = 0; ct < 16; ++ct) {
    const bool use = (ct < 8) ? use0 : use1;
    const int gc = panel * 32 + ct * 2;
    // cg=0 fragments (8 x dwordx4; L1-broadcast across the 8 waves)
    short8 bf[8];
#pragma unroll
    for (int ks = 0; ks < 8; ++ks)
      bf[ks] = *(const short8*)(lanep + ((size_t)(gc * 8 + ks) << 9));
    asm volatile("s_barrier" ::: "memory");  // converge; no LDS -> raw safe
    f32x4 acc0[4];
#pragma unroll
    for (int rg = 0; rg < 4; ++rg) acc0[rg] = (f32x4){0.f, 0.f, 0.f, 0.f};
#pragma unroll
    for (int ks = 0; ks < 8; ++ks)
#pragma unroll
      for (int rg = 0; rg < 4; ++rg) mfma_agpr(acc0[rg], af[rg][ks], bf[ks]);
    // cg=1 fragments (reuse bf regs)
#pragma unroll
    for (int ks = 0; ks < 8; ++ks)
      bf[ks] =
          *(const short8*)(lanep + ((size_t)((gc + 1) * 8 + ks) << 9));
    f32x4 acc1[4];
#pragma unroll
    for (int rg = 0; rg < 4; ++rg) acc1[rg] = (f32x4){0.f, 0.f, 0.f, 0.f};
#pragma unroll
    for (int ks = 0; ks < 8; ++ks)
#pragma unroll
      for (int rg = 0; rg < 4; ++rg) mfma_agpr(acc1[rg], af[rg][ks], bf[ks]);
    if (use) {
#pragma unroll
      for (int rg = 0; rg < 4; ++rg)
#pragma unroll
        for (int r = 0; r < 4; ++r)
          sacc[rg][r] += exp_2am2(acc0[rg][r]) + exp_2am2(acc1[rg][r]);
    }
  }

  // Row-sum over the 16 l16 lanes (32 cols folded into sacc already),
  // then one atomicAdd per row (16 panel contenders per ns entry).
#pragma unroll
  for (int rg = 0; rg < 4; ++rg)
#pragma unroll
    for (int r = 0; r < 4; ++r) {
      float v = sacc[rg][r];
      v += __shfl_xor(v, 1, 64);
      v += __shfl_xor(v, 2, 64);
      v += __shfl_xor(v, 4, 64);
      v += __shfl_xor(v, 8, 64);
      if (l16 == 0) atomicAdd(&ns[rowbase + rg * 16 + q * 4 + r], v);
    }
}

// ---------------- K4: positive sweep -> loss (LDS-free, list-driven) ------
__global__ __launch_bounds__(256, 2) void k_pos(
    const unsigned short* __restrict__ F2, const float* __restrict__ ns,
    const int* __restrict__ nact, const ushort2* __restrict__ list,
    const float* __restrict__ cscale, float* __restrict__ out) {
  const int tid = (int)threadIdx.x;
  const int w = tid >> 6, lane = tid & 63, q = lane >> 4, l16 = lane & 15;
  __shared__ float s_pos[4];
  const int n = *nact;
  const unsigned short* lanep = F2 + ((q * 16 + l16) << 3);

  float pos = 0.f;
  for (int idx = (int)blockIdx.x * 4 + w; idx < n;
       idx += (int)gridDim.x * 4) {
    const ushort2 e = list[idx];
    const int r32 = e.x, c32 = e.y;
    const int ga = r32 * 2, gb = c32 * 2;
    short8 af[2][8], bf[2][8];
#pragma unroll
    for (int rg = 0; rg < 2; ++rg)
#pragma unroll
      for (int ks = 0; ks < 8; ++ks) {
        af[rg][ks] =
            *(const short8*)(lanep + ((size_t)((ga + rg) * 8 + ks) << 9));
        bf[rg][ks] =
            *(const short8*)(lanep + ((size_t)((gb + rg) * 8 + ks) << 9));
      }
    float nsv[2][4];
#pragma unroll
    for (int rg = 0; rg < 2; ++rg)
#pragma unroll
      for (int r = 0; r < 4; ++r)
        nsv[rg][r] = ns[r32 * 32 + rg * 16 + q * 4 + r];
    const float scale = cscale[r32 >> 3];

    f32x4 a00 = {0.f, 0.f, 0.f, 0.f}, a01 = a00, a10 = a00, a11 = a00;
#pragma unroll
    for (int ks = 0; ks < 8; ++ks) {
      a00 = __builtin_amdgcn_mfma_f32_16x16x32_bf16(af[0][ks], bf[0][ks], a00,
                                                    0, 0, 0);
      a01 = __builtin_amdgcn_mfma_f32_16x16x32_bf16(af[0][ks], bf[1][ks], a01,
                                                    0, 0, 0);
      a10 = __builtin_amdgcn_mfma_f32_16x16x32_bf16(af[1][ks], bf[0][ks], a10,
                                                    0, 0, 0);
      a11 = __builtin_amdgcn_mfma_f32_16x16x32_bf16(af[1][ks], bf[1][ks], a11,
                                                    0, 0, 0);
    }
    float tpos = 0.f;
#pragma unroll
    for (int rg = 0; rg < 2; ++rg)
#pragma unroll
      for (int cg = 0; cg < 2; ++cg) {
        const f32x4 acc =
            (rg == 0) ? (cg == 0 ? a00 : a01) : (cg == 0 ? a10 : a11);
        const int jc = c32 * 32 + cg * 16 + l16;
#pragma unroll
        for (int r = 0; r < 4; ++r) {
          const int i = r32 * 32 + rg * 16 + q * 4 + r;
          if (i != jc) {
            float d = fmaf(acc[r], 2.f, -2.f);
            tpos += d - __logf(exp_2am2(acc[r]) + nsv[rg][r]);
          }
        }
      }
    pos += scale * tpos;
  }

#pragma unroll
  for (int m = 1; m < 64; m <<= 1) pos += __shfl_xor(pos, m, 64);
  if (lane == 0) s_pos[w] = pos;
  __syncthreads();
  if (tid == 0)
    atomicAdd(out, -(s_pos[0] + s_pos[1] + s_pos[2] + s_pos[3]));
}

extern "C" void kernel_launch(void* const* d_in, const int* in_sizes, int n_in,
                              void* d_out, int out_size, void* d_ws,
                              size_t ws_size, hipStream_t stream) {
  const float* feat = (const float*)d_in[0];
  const int* binds = (const int*)d_in[1];
  const int* sinds = (const int*)d_in[2];
  const int* labels = (const int*)d_in[3];
  float* out = (float*)d_out;
  unsigned short* FT = (unsigned short*)d_ws;            // 4 MB  [256][8192]
  unsigned short* F2 = FT + (size_t)kC * kM;             // 4 MB  fragment fmt
  float* ns = (float*)(F2 + (size_t)kM * kC);            // 32 KB [8192]
  int* nact = (int*)(ns + kM);                           // 4 B (+pad)
  float* cscale = (float*)(nact + 8);                    // 128 B [32]
  ushort2* list = (ushort2*)(cscale + 32);               // <=256 KB [65536]

  k_prep<<<64, 256, 0, stream>>>(labels, ns, out, out_size, nact, list, cscale);
  k_gather<<<dim3(8, kC), 256, 0, stream>>>(feat, binds, sinds, FT);
  k_norm<<<kM / 32, 256, 0, stream>>>(FT, F2);
  k_neg<<<256, 512, 0, stream>>>(F2, labels, ns);
  k_pos<<<512, 256, 0, stream>>>(F2, ns, nact, list, cscale, out);
}

// Round 10
// 165.332 us; speedup vs baseline: 1.1351x; 1.0632x over previous
//
#include <hip/hip_runtime.h>
#include <hip/hip_bf16.h>

// DenseContrastiveLossV2 on MI355X — round 11.
// Round-10 verdict: every 64-row-wave variant (LDS / L1 / AGPR) sits at
// 45-58us, MfmaUtil 21-28%. Root cause: arithmetic intensity is fixed by
// rows/wave (64 FLOP per B-byte) -> B-path demand ~83% of L1 BW, and the
// 2-waves/SIMD register budget can't overlap load and MFMA phases.
// Fixes (both levers that remain):
//  (1) SYMMETRY: d(i,j)=d(j,i) bitwise -> enumerate ~470 negative t-pairs
//      (ti<tj, labels differ); each 256x256 tile feeds exp row-sums to
//      ns[ti rows] AND col-sums to ns[tj rows]. MFMA work halves (floor
//      16.6 -> 7.6us). Diagonal/same-label pairs are never negatives, so
//      the label mask is exactly the pair list.
//  (2) LDS B-broadcast at 128 B/cyc (2x L1) with T3-minimum dbuf order
//      (barrier -> issue prefetch -> compute), af[2][8] (64 VGPR) sourced
//      from the soon-overwritten LDS (round-6-proven residency, VGPR=88).
// K0 k_prep   : zero ns/out, cscale, pos-pair list + NEG t-pair list.
// K1 k_gather : unchanged.
// K2 k_norm   : -> F2 fragment layout (unchanged).
// K3 k_neg    : triangle t-pair jobs; 8 waves x 32 rows; row+col sums.
// K4 k_pos    : unchanged (list-driven, off-profile).

namespace {

constexpr int kC = 256;
constexpr int kHW = 96 * 96;   // 9216
constexpr int kT = 32;
constexpr int kV = 256;
constexpr int kM = kT * kV;    // 8192

typedef __attribute__((ext_vector_type(8))) short short8;  // 8 bf16
typedef __attribute__((ext_vector_type(4))) float f32x4;

__device__ inline unsigned short f2bf(float x) {
  __hip_bfloat16 h = __float2bfloat16(x);
  return __builtin_bit_cast(unsigned short, h);
}
__device__ inline float bf2f(unsigned short u) {
  unsigned int v = ((unsigned int)u) << 16;
  return __builtin_bit_cast(float, v);
}
// exp(2a-2) = exp2(a*2log2e - 2log2e); one fma + native v_exp_f32.
__device__ inline float exp_2am2(float a) {
  return exp2f(fmaf(a, 2.8853900818f, -2.8853900818f));
}
__device__ inline void load_lds16(const unsigned short* g, unsigned short* l) {
  __builtin_amdgcn_global_load_lds(
      (const __attribute__((address_space(1))) void*)g,
      (__attribute__((address_space(3))) void*)l, 16, 0, 0);
}

// F2 fragment layout: for 16-vec group g, k-group ks (k = ks*32+q*8+e),
// lane (q*16+l16) stores elems e=0..7 of F[v=g*16+l16][c=ks*32+q*8+e].
// Slot offset in shorts: ((g*8+ks)<<9) + ((q*16+l16)<<3). One fragment =
// one 16B coalesced access; a g-group (16 rows x 256 k) = 8 KB contiguous.

// Stage one 2-g-group tile (32 cols x 256 k = 16 KB) into LDS, 512 thr.
__device__ inline void stage_ct(const unsigned short* __restrict__ F2,
                                unsigned short* lds, int g0, int tid) {
#pragma unroll
  for (int i = 0; i < 2; ++i) {
    const int nslot = i * 512 + tid;  // 16B slots 0..1023
    load_lds16(F2 + (((size_t)g0 * 8) << 9) + ((size_t)nslot << 3),
               lds + ((size_t)nslot << 3));
  }
}
// Stage 4 g-groups (64 rows, 32 KB) across both Bt buffers (prologue only).
__device__ inline void stage_a(const unsigned short* __restrict__ F2,
                               unsigned short* lds, int g0, int tid) {
#pragma unroll
  for (int i = 0; i < 4; ++i) {
    const int nslot = i * 512 + tid;  // 16B slots 0..2047
    load_lds16(F2 + (((size_t)g0 * 8) << 9) + ((size_t)nslot << 3),
               lds + ((size_t)nslot << 3));
  }
}

}  // namespace

// ---------------- K0: prep (zero ns/out, scales, pos + neg lists) ---------
__global__ __launch_bounds__(256) void k_prep(
    const int* __restrict__ labels, float* __restrict__ ns,
    float* __restrict__ out, int out_size, int* __restrict__ nact,
    ushort2* __restrict__ list, float* __restrict__ cscale,
    int* __restrict__ nneg, ushort2* __restrict__ neglist) {
  const int tid = (int)threadIdx.x;
  const int b = (int)blockIdx.x;
  for (int i = b * 256 + tid; i < kM; i += 64 * 256) ns[i] = 0.f;
  if (b != 0) return;
  __shared__ int s_lab[kT];
  if (tid < kT) s_lab[tid] = labels[tid];
  if (tid == 0) {
    *nact = 0;
    *nneg = 0;
  }
  for (int i = tid; i < out_size; i += 256) out[i] = 0.f;
  __syncthreads();
  if (tid < kT) {
    int m = 0;
    for (int u = 0; u < kT; ++u) m += (s_lab[u] == s_lab[tid]) ? 1 : 0;
    cscale[tid] = 1.f / ((float)(m * kV - 1) * (float)kM);
  }
  for (int p = tid; p < kT * kT; p += 256) {
    const int ti = p >> 5, tj = p & 31;
    if (s_lab[ti] == s_lab[tj]) {
      int base = atomicAdd(nact, 64);  // 8x8 (r32,c32) sub-tiles per t-pair
#pragma unroll
      for (int a = 0; a < 8; ++a)
#pragma unroll
        for (int bb = 0; bb < 8; ++bb) {
          ushort2 e;
          e.x = (unsigned short)(ti * 8 + a);  // r32 0..255
          e.y = (unsigned short)(tj * 8 + bb); // c32 0..255
          list[base + a * 8 + bb] = e;
        }
    } else if (ti < tj) {  // negative t-pair (upper triangle)
      int idx = atomicAdd(nneg, 1);
      ushort2 e;
      e.x = (unsigned short)ti;
      e.y = (unsigned short)tj;
      neglist[idx] = e;
    }
  }
}

// ---------------- K1: gather (coalesced row staging) ----------------
__global__ __launch_bounds__(256) void k_gather(
    const float* __restrict__ feat, const int* __restrict__ binds,
    const int* __restrict__ sinds, unsigned short* __restrict__ FT) {
  const int b = (int)blockIdx.x;   // 0..7
  const int c = (int)blockIdx.y;   // 0..255
  __shared__ alignas(16) float row[kHW];
  __shared__ int s_match[kT + 1];
  if (threadIdx.x == 0) {
    int cnt = 0;
    for (int t = 0; t < kT; ++t)
      if (binds[t] == b) s_match[1 + cnt++] = t;
    s_match[0] = cnt;
  }
  __syncthreads();
  const int cnt = s_match[0];
  if (cnt == 0) return;
  const float4* src4 = (const float4*)(feat + ((size_t)b * kC + c) * kHW);
  for (int i = (int)threadIdx.x; i < kHW / 4; i += 256)
    ((float4*)row)[i] = src4[i];
  __syncthreads();
  unsigned short* dst = FT + (size_t)c * kM;
  for (int mi = 1; mi <= cnt; ++mi) {
    const int t = s_match[mi];
    const int p = sinds[t * kV + threadIdx.x];
    dst[t * kV + threadIdx.x] = f2bf(row[p]);
  }
}

// ---------------- K2: transpose + normalize -> F2 fragment layout ---------
__global__ __launch_bounds__(256) void k_norm(
    const unsigned short* __restrict__ FT, unsigned short* __restrict__ F2) {
  constexpr int PAD = 40;  // 32 vecs + 8 pad (80 B rows: breaks bank aliasing)
  const int v0 = (int)blockIdx.x * 32;
  __shared__ alignas(16) unsigned short tile[kC][PAD];
  __shared__ float part[8][32];
  __shared__ float s_inv[32];
  const int tid = (int)threadIdx.x;
  {
    const int p4 = tid & 3, cb = tid >> 2;  // 4x16B per 64B c-row
    for (int c = cb; c < kC; c += 64) {
      int4 d = *(const int4*)(FT + (size_t)c * kM + v0 + p4 * 8);
      *(int4*)&tile[c][p4 * 8] = d;
    }
  }
  __syncthreads();
  {
    const int v = tid & 31, oct = tid >> 5;
    float ss = 0.f;
    for (int c = oct * 32; c < oct * 32 + 32; ++c) {
      float x = bf2f(tile[c][v]);
      ss += x * x;
    }
    part[oct][v] = ss;
  }
  __syncthreads();
  if (tid < 32) {
    float ss = 0.f;
#pragma unroll
    for (int o = 0; o < 8; ++o) ss += part[o][tid];
    s_inv[tid] = 1.0f / fmaxf(sqrtf(ss), 1e-12f);
  }
  __syncthreads();
#pragma unroll
  for (int p = 0; p < 4; ++p) {
    const int slot = p * 256 + tid;  // 0..1023
    const int l16s = slot & 15;
    const int qs = (slot >> 4) & 3;
    const int kss = (slot >> 6) & 7;
    const int gl = slot >> 9;  // 0..1
    const int vloc = gl * 16 + l16s;
    const int c0 = kss * 32 + qs * 8;
    const float inv = s_inv[vloc];
    alignas(16) unsigned short o[8];
#pragma unroll
    for (int k = 0; k < 8; ++k) o[k] = f2bf(bf2f(tile[c0 + k][vloc]) * inv);
    *(int4*)(F2 + ((size_t)(((v0 >> 4) + gl) * 8 + kss) << 9) +
             ((qs * 16 + l16s) << 3)) = *(const int4*)o;
  }
}

// ---------------- K3: negative sweep (triangle t-pairs) -> ns -------------
// 512 blocks x 512 thr (1 block/CU resident). Grid-stride over ~470 neg
// t-pair jobs. Per job (ti,tj): 8 waves x 32 rows of ti; B = tj's 256 cols
// in 8 double-buffered 16 KB LDS tiles (T3 order: barrier -> issue ->
// compute). Each exp value feeds BOTH rowacc (ns[ti rows]) and colacc
// (ns[tj rows]) -- the symmetry win. af[2][8] is LDS-sourced then the
// buffer is overwritten => register-resident (round-6 mechanism).
__global__ __launch_bounds__(512, 2) void k_neg(
    const unsigned short* __restrict__ F2, const int* __restrict__ nneg,
    const ushort2* __restrict__ neglist, float* __restrict__ ns) {
  const int tid = (int)threadIdx.x;
  const int w = tid >> 6, lane = tid & 63, q = lane >> 4, l16 = lane & 15;
  __shared__ alignas(16) unsigned short Bt[2][8192];  // 2 x 16 KB
  __shared__ float colacc[256];
  const int n = *nneg;
  const int laneofs = (q * 16 + l16) << 3;  // fragment lane offset (shorts)

  for (int job = (int)blockIdx.x; job < n; job += (int)gridDim.x) {
    const ushort2 e = neglist[job];
    const int ti = e.x, tj = e.y;
    if (tid < 256) colacc[tid] = 0.f;

    // --- A prologue: 4 passes x 32 KB (64 rows) through both Bt buffers.
    // Waves 2p, 2p+1 read their af in pass p; Bt is overwritten afterwards
    // => compiler must keep af in registers (cannot remat an LDS load past
    // the intervening LDS stores).
    short8 af[2][8];
#pragma unroll 1
    for (int p = 0; p < 4; ++p) {
      stage_a(F2, &Bt[0][0], ti * 16 + p * 4, tid);
      __syncthreads();  // staging drained (vmcnt(0) before barrier)
      if ((w >> 1) == p) {
        const int lg = (w & 1) * 2;  // local g-group 0 or 2
#pragma unroll
        for (int rg = 0; rg < 2; ++rg)
#pragma unroll
          for (int ks = 0; ks < 8; ++ks)
            af[rg][ks] = *(const short8*)(
                &Bt[0][0] + ((size_t)((lg + rg) * 8 + ks) << 9) + laneofs);
      }
      __syncthreads();  // readers done before next pass overwrites
    }

    // --- B ct-loop: 8 tiles of 32 cols, double-buffered.
    stage_ct(F2, &Bt[0][0], tj * 16, tid);  // prologue prefetch ct0
    float rowacc[2][4] = {};
    int cur = 0;
#pragma unroll 1
    for (int ct = 0; ct < 8; ++ct) {
      __syncthreads();  // drains stage(ct); prev-tile readers are done
      if (ct < 7) stage_ct(F2, &Bt[cur ^ 1][0], tj * 16 + (ct + 1) * 2, tid);
      const unsigned short* bbase = &Bt[cur][0] + laneofs;
      f32x4 a00 = {0.f, 0.f, 0.f, 0.f}, a01 = a00, a10 = a00, a11 = a00;
#pragma unroll
      for (int ks = 0; ks < 8; ++ks) {
        short8 b0 = *(const short8*)(bbase + ((size_t)ks << 9));
        short8 b1 = *(const short8*)(bbase + ((size_t)(8 + ks) << 9));
        a00 = __builtin_amdgcn_mfma_f32_16x16x32_bf16(af[0][ks], b0, a00,
                                                      0, 0, 0);
        a01 = __builtin_amdgcn_mfma_f32_16x16x32_bf16(af[0][ks], b1, a01,
                                                      0, 0, 0);
        a10 = __builtin_amdgcn_mfma_f32_16x16x32_bf16(af[1][ks], b0, a10,
                                                      0, 0, 0);
        a11 = __builtin_amdgcn_mfma_f32_16x16x32_bf16(af[1][ks], b1, a11,
                                                      0, 0, 0);
      }
      float col0 = 0.f, col1 = 0.f;
#pragma unroll
      for (int r = 0; r < 4; ++r) {
        float e00 = exp_2am2(a00[r]), e01 = exp_2am2(a01[r]);
        float e10 = exp_2am2(a10[r]), e11 = exp_2am2(a11[r]);
        rowacc[0][r] += e00 + e01;
        rowacc[1][r] += e10 + e11;
        col0 += e00 + e10;
        col1 += e01 + e11;
      }
      // col partials: reduce over q (rows within wave), LDS-accumulate.
      col0 += __shfl_xor(col0, 16, 64);
      col0 += __shfl_xor(col0, 32, 64);
      col1 += __shfl_xor(col1, 16, 64);
      col1 += __shfl_xor(col1, 32, 64);
      if (q == 0) {
        atomicAdd(&colacc[ct * 32 + l16], col0);
        atomicAdd(&colacc[ct * 32 + 16 + l16], col1);
      }
      cur ^= 1;
    }
    __syncthreads();  // colacc complete
    // flush cols -> ns[tj rows]
    if (tid < 256) atomicAdd(&ns[tj * 256 + tid], colacc[tid]);
    // flush rows -> ns[ti rows]: reduce over the 16 column lanes
#pragma unroll
    for (int rg = 0; rg < 2; ++rg)
#pragma unroll
      for (int r = 0; r < 4; ++r) {
        float v = rowacc[rg][r];
        v += __shfl_xor(v, 1, 64);
        v += __shfl_xor(v, 2, 64);
        v += __shfl_xor(v, 4, 64);
        v += __shfl_xor(v, 8, 64);
        if (l16 == 0)
          atomicAdd(&ns[ti * 256 + w * 32 + rg * 16 + q * 4 + r], v);
      }
    __syncthreads();  // flush done before next job resets colacc
  }
}

// ---------------- K4: positive sweep -> loss (LDS-free, list-driven) ------
__global__ __launch_bounds__(256, 2) void k_pos(
    const unsigned short* __restrict__ F2, const float* __restrict__ ns,
    const int* __restrict__ nact, const ushort2* __restrict__ list,
    const float* __restrict__ cscale, float* __restrict__ out) {
  const int tid = (int)threadIdx.x;
  const int w = tid >> 6, lane = tid & 63, q = lane >> 4, l16 = lane & 15;
  __shared__ float s_pos[4];
  const int n = *nact;
  const unsigned short* lanep = F2 + ((q * 16 + l16) << 3);

  float pos = 0.f;
  for (int idx = (int)blockIdx.x * 4 + w; idx < n;
       idx += (int)gridDim.x * 4) {
    const ushort2 e = list[idx];
    const int r32 = e.x, c32 = e.y;
    const int ga = r32 * 2, gb = c32 * 2;
    short8 af[2][8], bf[2][8];
#pragma unroll
    for (int rg = 0; rg < 2; ++rg)
#pragma unroll
      for (int ks = 0; ks < 8; ++ks) {
        af[rg][ks] =
            *(const short8*)(lanep + ((size_t)((ga + rg) * 8 + ks) << 9));
        bf[rg][ks] =
            *(const short8*)(lanep + ((size_t)((gb + rg) * 8 + ks) << 9));
      }
    float nsv[2][4];
#pragma unroll
    for (int rg = 0; rg < 2; ++rg)
#pragma unroll
      for (int r = 0; r < 4; ++r)
        nsv[rg][r] = ns[r32 * 32 + rg * 16 + q * 4 + r];
    const float scale = cscale[r32 >> 3];

    f32x4 a00 = {0.f, 0.f, 0.f, 0.f}, a01 = a00, a10 = a00, a11 = a00;
#pragma unroll
    for (int ks = 0; ks < 8; ++ks) {
      a00 = __builtin_amdgcn_mfma_f32_16x16x32_bf16(af[0][ks], bf[0][ks], a00,
                                                    0, 0, 0);
      a01 = __builtin_amdgcn_mfma_f32_16x16x32_bf16(af[0][ks], bf[1][ks], a01,
                                                    0, 0, 0);
      a10 = __builtin_amdgcn_mfma_f32_16x16x32_bf16(af[1][ks], bf[0][ks], a10,
                                                    0, 0, 0);
      a11 = __builtin_amdgcn_mfma_f32_16x16x32_bf16(af[1][ks], bf[1][ks], a11,
                                                    0, 0, 0);
    }
    float tpos = 0.f;
#pragma unroll
    for (int rg = 0; rg < 2; ++rg)
#pragma unroll
      for (int cg = 0; cg < 2; ++cg) {
        const f32x4 acc =
            (rg == 0) ? (cg == 0 ? a00 : a01) : (cg == 0 ? a10 : a11);
        const int jc = c32 * 32 + cg * 16 + l16;
#pragma unroll
        for (int r = 0; r < 4; ++r) {
          const int i = r32 * 32 + rg * 16 + q * 4 + r;
          if (i != jc) {
            float d = fmaf(acc[r], 2.f, -2.f);
            tpos += d - __logf(exp_2am2(acc[r]) + nsv[rg][r]);
          }
        }
      }
    pos += scale * tpos;
  }

#pragma unroll
  for (int m = 1; m < 64; m <<= 1) pos += __shfl_xor(pos, m, 64);
  if (lane == 0) s_pos[w] = pos;
  __syncthreads();
  if (tid == 0)
    atomicAdd(out, -(s_pos[0] + s_pos[1] + s_pos[2] + s_pos[3]));
}

extern "C" void kernel_launch(void* const* d_in, const int* in_sizes, int n_in,
                              void* d_out, int out_size, void* d_ws,
                              size_t ws_size, hipStream_t stream) {
  const float* feat = (const float*)d_in[0];
  const int* binds = (const int*)d_in[1];
  const int* sinds = (const int*)d_in[2];
  const int* labels = (const int*)d_in[3];
  float* out = (float*)d_out;
  unsigned short* FT = (unsigned short*)d_ws;            // 4 MB  [256][8192]
  unsigned short* F2 = FT + (size_t)kC * kM;             // 4 MB  fragment fmt
  float* ns = (float*)(F2 + (size_t)kM * kC);            // 32 KB [8192]
  int* nact = (int*)(ns + kM);                           // 4 B (+pad)
  float* cscale = (float*)(nact + 8);                    // 128 B [32]
  ushort2* list = (ushort2*)(cscale + 32);               // 256 KB [65536]
  int* nneg = (int*)(list + 65536);                      // 4 B (+pad)
  ushort2* neglist = (ushort2*)(nneg + 8);               // 2 KB [512]

  k_prep<<<64, 256, 0, stream>>>(labels, ns, out, out_size, nact, list,
                                 cscale, nneg, neglist);
  k_gather<<<dim3(8, kC), 256, 0, stream>>>(feat, binds, sinds, FT);
  k_norm<<<kM / 32, 256, 0, stream>>>(FT, F2);
  k_neg<<<512, 512, 0, stream>>>(F2, nneg, neglist, ns);
  k_pos<<<512, 256, 0, stream>>>(F2, ns, nact, list, cscale, out);
}

// Round 11
// 163.231 us; speedup vs baseline: 1.1497x; 1.0129x over previous
//
#include <hip/hip_runtime.h>
#include <hip/hip_bf16.h>

// DenseContrastiveLossV2 on MI355X — round 12.
// Round-11: symmetry+LDS-broadcast k_neg worked (total 175.8 -> 165.3us);
// top-5 now all harness fillBufferAligned (~96us/iter fixed) -> profiler-
// blind below 47us, judge by total. Remaining lever: k_pos is still DENSE
// over same-label ordered pairs. This round: symmetric k_pos — each tile
// computed once; row side evaluates log_prob[i,j] with ns_i, mirror side
// evaluates log_prob[j,i] with ns_j (d is symmetric). Tiles 5376 -> ~2816.
// Mirror flag in list[].y bit 15; diagonal (a==b, ti==tj) tiles un-mirrored
// with the i!=j check (= pos_mask eq*(1-I) exactly).
// K0 k_prep   : zero ns/out, cscale, symmetric pos list + neg t-pair list.
// K1 k_gather : unchanged (r11).
// K2 k_norm   : unchanged (r11).
// K3 k_neg    : unchanged (r11, triangle t-pairs, row+col sums).
// K4 k_pos    : symmetric list consumer (row + mirrored col contributions).

namespace {

constexpr int kC = 256;
constexpr int kHW = 96 * 96;   // 9216
constexpr int kT = 32;
constexpr int kV = 256;
constexpr int kM = kT * kV;    // 8192

typedef __attribute__((ext_vector_type(8))) short short8;  // 8 bf16
typedef __attribute__((ext_vector_type(4))) float f32x4;

__device__ inline unsigned short f2bf(float x) {
  __hip_bfloat16 h = __float2bfloat16(x);
  return __builtin_bit_cast(unsigned short, h);
}
__device__ inline float bf2f(unsigned short u) {
  unsigned int v = ((unsigned int)u) << 16;
  return __builtin_bit_cast(float, v);
}
// exp(2a-2) = exp2(a*2log2e - 2log2e); one fma + native v_exp_f32.
__device__ inline float exp_2am2(float a) {
  return exp2f(fmaf(a, 2.8853900818f, -2.8853900818f));
}
__device__ inline void load_lds16(const unsigned short* g, unsigned short* l) {
  __builtin_amdgcn_global_load_lds(
      (const __attribute__((address_space(1))) void*)g,
      (__attribute__((address_space(3))) void*)l, 16, 0, 0);
}

// F2 fragment layout: for 16-vec group g, k-group ks (k = ks*32+q*8+e),
// lane (q*16+l16) stores elems e=0..7 of F[v=g*16+l16][c=ks*32+q*8+e].
// Slot offset in shorts: ((g*8+ks)<<9) + ((q*16+l16)<<3). One fragment =
// one 16B coalesced access; a g-group (16 rows x 256 k) = 8 KB contiguous.

// Stage one 2-g-group tile (32 cols x 256 k = 16 KB) into LDS, 512 thr.
__device__ inline void stage_ct(const unsigned short* __restrict__ F2,
                                unsigned short* lds, int g0, int tid) {
#pragma unroll
  for (int i = 0; i < 2; ++i) {
    const int nslot = i * 512 + tid;  // 16B slots 0..1023
    load_lds16(F2 + (((size_t)g0 * 8) << 9) + ((size_t)nslot << 3),
               lds + ((size_t)nslot << 3));
  }
}
// Stage 4 g-groups (64 rows, 32 KB) across both Bt buffers (prologue only).
__device__ inline void stage_a(const unsigned short* __restrict__ F2,
                               unsigned short* lds, int g0, int tid) {
#pragma unroll
  for (int i = 0; i < 4; ++i) {
    const int nslot = i * 512 + tid;  // 16B slots 0..2047
    load_lds16(F2 + (((size_t)g0 * 8) << 9) + ((size_t)nslot << 3),
               lds + ((size_t)nslot << 3));
  }
}

}  // namespace

// ---------------- K0: prep (zero ns/out, scales, pos + neg lists) ---------
__global__ __launch_bounds__(256) void k_prep(
    const int* __restrict__ labels, float* __restrict__ ns,
    float* __restrict__ out, int out_size, int* __restrict__ nact,
    ushort2* __restrict__ list, float* __restrict__ cscale,
    int* __restrict__ nneg, ushort2* __restrict__ neglist) {
  const int tid = (int)threadIdx.x;
  const int b = (int)blockIdx.x;
  for (int i = b * 256 + tid; i < kM; i += 64 * 256) ns[i] = 0.f;
  if (b != 0) return;
  __shared__ int s_lab[kT];
  if (tid < kT) s_lab[tid] = labels[tid];
  if (tid == 0) {
    *nact = 0;
    *nneg = 0;
  }
  for (int i = tid; i < out_size; i += 256) out[i] = 0.f;
  __syncthreads();
  if (tid < kT) {
    int m = 0;
    for (int u = 0; u < kT; ++u) m += (s_lab[u] == s_lab[tid]) ? 1 : 0;
    cscale[tid] = 1.f / ((float)(m * kV - 1) * (float)kM);
  }
  for (int p = tid; p < kT * kT; p += 256) {
    const int ti = p >> 5, tj = p & 31;
    if (s_lab[ti] == s_lab[tj]) {
      if (ti < tj) {
        // cross t-pair: 64 sub-tiles, all mirrored (i != j guaranteed).
        int base = atomicAdd(nact, 64);
#pragma unroll
        for (int a = 0; a < 8; ++a)
#pragma unroll
          for (int bb = 0; bb < 8; ++bb) {
            ushort2 e;
            e.x = (unsigned short)(ti * 8 + a);
            e.y = (unsigned short)((tj * 8 + bb) | 0x8000);
            list[base + a * 8 + bb] = e;
          }
      } else if (ti == tj) {
        // diagonal t: a<b mirrored (28) + a==b un-mirrored w/ i!=j (8).
        int base = atomicAdd(nact, 36);
        int k = 0;
        for (int a = 0; a < 8; ++a) {
          ushort2 d;
          d.x = (unsigned short)(ti * 8 + a);
          d.y = (unsigned short)(ti * 8 + a);  // mirror=0
          list[base + k++] = d;
          for (int bb = a + 1; bb < 8; ++bb) {
            ushort2 e;
            e.x = (unsigned short)(ti * 8 + a);
            e.y = (unsigned short)((ti * 8 + bb) | 0x8000);
            list[base + k++] = e;
          }
        }
      }
    } else if (ti < tj) {  // negative t-pair (upper triangle)
      int idx = atomicAdd(nneg, 1);
      ushort2 e;
      e.x = (unsigned short)ti;
      e.y = (unsigned short)tj;
      neglist[idx] = e;
    }
  }
}

// ---------------- K1: gather (coalesced row staging) ----------------
__global__ __launch_bounds__(256) void k_gather(
    const float* __restrict__ feat, const int* __restrict__ binds,
    const int* __restrict__ sinds, unsigned short* __restrict__ FT) {
  const int b = (int)blockIdx.x;   // 0..7
  const int c = (int)blockIdx.y;   // 0..255
  __shared__ alignas(16) float row[kHW];
  __shared__ int s_match[kT + 1];
  if (threadIdx.x == 0) {
    int cnt = 0;
    for (int t = 0; t < kT; ++t)
      if (binds[t] == b) s_match[1 + cnt++] = t;
    s_match[0] = cnt;
  }
  __syncthreads();
  const int cnt = s_match[0];
  if (cnt == 0) return;
  const float4* src4 = (const float4*)(feat + ((size_t)b * kC + c) * kHW);
  for (int i = (int)threadIdx.x; i < kHW / 4; i += 256)
    ((float4*)row)[i] = src4[i];
  __syncthreads();
  unsigned short* dst = FT + (size_t)c * kM;
  for (int mi = 1; mi <= cnt; ++mi) {
    const int t = s_match[mi];
    const int p = sinds[t * kV + threadIdx.x];
    dst[t * kV + threadIdx.x] = f2bf(row[p]);
  }
}

// ---------------- K2: transpose + normalize -> F2 fragment layout ---------
__global__ __launch_bounds__(256) void k_norm(
    const unsigned short* __restrict__ FT, unsigned short* __restrict__ F2) {
  constexpr int PAD = 40;  // 32 vecs + 8 pad (80 B rows: breaks bank aliasing)
  const int v0 = (int)blockIdx.x * 32;
  __shared__ alignas(16) unsigned short tile[kC][PAD];
  __shared__ float part[8][32];
  __shared__ float s_inv[32];
  const int tid = (int)threadIdx.x;
  {
    const int p4 = tid & 3, cb = tid >> 2;  // 4x16B per 64B c-row
    for (int c = cb; c < kC; c += 64) {
      int4 d = *(const int4*)(FT + (size_t)c * kM + v0 + p4 * 8);
      *(int4*)&tile[c][p4 * 8] = d;
    }
  }
  __syncthreads();
  {
    const int v = tid & 31, oct = tid >> 5;
    float ss = 0.f;
    for (int c = oct * 32; c < oct * 32 + 32; ++c) {
      float x = bf2f(tile[c][v]);
      ss += x * x;
    }
    part[oct][v] = ss;
  }
  __syncthreads();
  if (tid < 32) {
    float ss = 0.f;
#pragma unroll
    for (int o = 0; o < 8; ++o) ss += part[o][tid];
    s_inv[tid] = 1.0f / fmaxf(sqrtf(ss), 1e-12f);
  }
  __syncthreads();
#pragma unroll
  for (int p = 0; p < 4; ++p) {
    const int slot = p * 256 + tid;  // 0..1023
    const int l16s = slot & 15;
    const int qs = (slot >> 4) & 3;
    const int kss = (slot >> 6) & 7;
    const int gl = slot >> 9;  // 0..1
    const int vloc = gl * 16 + l16s;
    const int c0 = kss * 32 + qs * 8;
    const float inv = s_inv[vloc];
    alignas(16) unsigned short o[8];
#pragma unroll
    for (int k = 0; k < 8; ++k) o[k] = f2bf(bf2f(tile[c0 + k][vloc]) * inv);
    *(int4*)(F2 + ((size_t)(((v0 >> 4) + gl) * 8 + kss) << 9) +
             ((qs * 16 + l16s) << 3)) = *(const int4*)o;
  }
}

// ---------------- K3: negative sweep (triangle t-pairs) -> ns -------------
// (unchanged from round 11 — passed)
__global__ __launch_bounds__(512, 2) void k_neg(
    const unsigned short* __restrict__ F2, const int* __restrict__ nneg,
    const ushort2* __restrict__ neglist, float* __restrict__ ns) {
  const int tid = (int)threadIdx.x;
  const int w = tid >> 6, lane = tid & 63, q = lane >> 4, l16 = lane & 15;
  __shared__ alignas(16) unsigned short Bt[2][8192];  // 2 x 16 KB
  __shared__ float colacc[256];
  const int n = *nneg;
  const int laneofs = (q * 16 + l16) << 3;  // fragment lane offset (shorts)

  for (int job = (int)blockIdx.x; job < n; job += (int)gridDim.x) {
    const ushort2 e = neglist[job];
    const int ti = e.x, tj = e.y;
    if (tid < 256) colacc[tid] = 0.f;

    // A prologue: 4 passes x 32 KB through both Bt buffers; af LDS-sourced
    // then overwritten => register-resident (round-6 mechanism).
    short8 af[2][8];
#pragma unroll 1
    for (int p = 0; p < 4; ++p) {
      stage_a(F2, &Bt[0][0], ti * 16 + p * 4, tid);
      __syncthreads();  // staging drained (vmcnt(0) before barrier)
      if ((w >> 1) == p) {
        const int lg = (w & 1) * 2;  // local g-group 0 or 2
#pragma unroll
        for (int rg = 0; rg < 2; ++rg)
#pragma unroll
          for (int ks = 0; ks < 8; ++ks)
            af[rg][ks] = *(const short8*)(
                &Bt[0][0] + ((size_t)((lg + rg) * 8 + ks) << 9) + laneofs);
      }
      __syncthreads();  // readers done before next pass overwrites
    }

    // B ct-loop: 8 tiles of 32 cols, double-buffered (T3 order).
    stage_ct(F2, &Bt[0][0], tj * 16, tid);  // prologue prefetch ct0
    float rowacc[2][4] = {};
    int cur = 0;
#pragma unroll 1
    for (int ct = 0; ct < 8; ++ct) {
      __syncthreads();  // drains stage(ct); prev-tile readers are done
      if (ct < 7) stage_ct(F2, &Bt[cur ^ 1][0], tj * 16 + (ct + 1) * 2, tid);
      const unsigned short* bbase = &Bt[cur][0] + laneofs;
      f32x4 a00 = {0.f, 0.f, 0.f, 0.f}, a01 = a00, a10 = a00, a11 = a00;
#pragma unroll
      for (int ks = 0; ks < 8; ++ks) {
        short8 b0 = *(const short8*)(bbase + ((size_t)ks << 9));
        short8 b1 = *(const short8*)(bbase + ((size_t)(8 + ks) << 9));
        a00 = __builtin_amdgcn_mfma_f32_16x16x32_bf16(af[0][ks], b0, a00,
                                                      0, 0, 0);
        a01 = __builtin_amdgcn_mfma_f32_16x16x32_bf16(af[0][ks], b1, a01,
                                                      0, 0, 0);
        a10 = __builtin_amdgcn_mfma_f32_16x16x32_bf16(af[1][ks], b0, a10,
                                                      0, 0, 0);
        a11 = __builtin_amdgcn_mfma_f32_16x16x32_bf16(af[1][ks], b1, a11,
                                                      0, 0, 0);
      }
      float col0 = 0.f, col1 = 0.f;
#pragma unroll
      for (int r = 0; r < 4; ++r) {
        float e00 = exp_2am2(a00[r]), e01 = exp_2am2(a01[r]);
        float e10 = exp_2am2(a10[r]), e11 = exp_2am2(a11[r]);
        rowacc[0][r] += e00 + e01;
        rowacc[1][r] += e10 + e11;
        col0 += e00 + e10;
        col1 += e01 + e11;
      }
      col0 += __shfl_xor(col0, 16, 64);
      col0 += __shfl_xor(col0, 32, 64);
      col1 += __shfl_xor(col1, 16, 64);
      col1 += __shfl_xor(col1, 32, 64);
      if (q == 0) {
        atomicAdd(&colacc[ct * 32 + l16], col0);
        atomicAdd(&colacc[ct * 32 + 16 + l16], col1);
      }
      cur ^= 1;
    }
    __syncthreads();  // colacc complete
    if (tid < 256) atomicAdd(&ns[tj * 256 + tid], colacc[tid]);
#pragma unroll
    for (int rg = 0; rg < 2; ++rg)
#pragma unroll
      for (int r = 0; r < 4; ++r) {
        float v = rowacc[rg][r];
        v += __shfl_xor(v, 1, 64);
        v += __shfl_xor(v, 2, 64);
        v += __shfl_xor(v, 4, 64);
        v += __shfl_xor(v, 8, 64);
        if (l16 == 0)
          atomicAdd(&ns[ti * 256 + w * 32 + rg * 16 + q * 4 + r], v);
      }
    __syncthreads();  // flush done before next job resets colacc
  }
}

// ---------------- K4: positive sweep -> loss (symmetric, list-driven) -----
// Mirror tiles: one dot d serves log_prob[i,j] (ns_i, scale_i) AND
// log_prob[j,i] (ns_j, scale_j). Un-mirrored diagonal tiles keep the
// i!=j check (they contain both orderings natively).
__global__ __launch_bounds__(256, 2) void k_pos(
    const unsigned short* __restrict__ F2, const float* __restrict__ ns,
    const int* __restrict__ nact, const ushort2* __restrict__ list,
    const float* __restrict__ cscale, float* __restrict__ out) {
  const int tid = (int)threadIdx.x;
  const int w = tid >> 6, lane = tid & 63, q = lane >> 4, l16 = lane & 15;
  __shared__ float s_pos[4];
  const int n = *nact;
  const unsigned short* lanep = F2 + ((q * 16 + l16) << 3);

  float pos = 0.f;
  for (int idx = (int)blockIdx.x * 4 + w; idx < n;
       idx += (int)gridDim.x * 4) {
    const ushort2 e = list[idx];
    const int r32 = e.x;
    const int c32 = e.y & 0x7fff;
    const bool mirror = (e.y & 0x8000) != 0;
    const int ga = r32 * 2, gb = c32 * 2;
    short8 af[2][8], bf[2][8];
#pragma unroll
    for (int rg = 0; rg < 2; ++rg)
#pragma unroll
      for (int ks = 0; ks < 8; ++ks) {
        af[rg][ks] =
            *(const short8*)(lanep + ((size_t)((ga + rg) * 8 + ks) << 9));
        bf[rg][ks] =
            *(const short8*)(lanep + ((size_t)((gb + rg) * 8 + ks) << 9));
      }
    float nsv[2][4];
#pragma unroll
    for (int rg = 0; rg < 2; ++rg)
#pragma unroll
      for (int r = 0; r < 4; ++r)
        nsv[rg][r] = ns[r32 * 32 + rg * 16 + q * 4 + r];
    float nsc[2];
    nsc[0] = ns[c32 * 32 + l16];
    nsc[1] = ns[c32 * 32 + 16 + l16];
    const float scr = cscale[r32 >> 3];
    const float scc = cscale[c32 >> 3];

    f32x4 a00 = {0.f, 0.f, 0.f, 0.f}, a01 = a00, a10 = a00, a11 = a00;
#pragma unroll
    for (int ks = 0; ks < 8; ++ks) {
      a00 = __builtin_amdgcn_mfma_f32_16x16x32_bf16(af[0][ks], bf[0][ks], a00,
                                                    0, 0, 0);
      a01 = __builtin_amdgcn_mfma_f32_16x16x32_bf16(af[0][ks], bf[1][ks], a01,
                                                    0, 0, 0);
      a10 = __builtin_amdgcn_mfma_f32_16x16x32_bf16(af[1][ks], bf[0][ks], a10,
                                                    0, 0, 0);
      a11 = __builtin_amdgcn_mfma_f32_16x16x32_bf16(af[1][ks], bf[1][ks], a11,
                                                    0, 0, 0);
    }
    float tr = 0.f, tc = 0.f;
#pragma unroll
    for (int rg = 0; rg < 2; ++rg)
#pragma unroll
      for (int cg = 0; cg < 2; ++cg) {
        const f32x4 acc =
            (rg == 0) ? (cg == 0 ? a00 : a01) : (cg == 0 ? a10 : a11);
#pragma unroll
        for (int r = 0; r < 4; ++r) {
          const float d = fmaf(acc[r], 2.f, -2.f);
          const float ee = exp_2am2(acc[r]);
          if (mirror) {
            tr += d - __logf(ee + nsv[rg][r]);
            tc += d - __logf(ee + nsc[cg]);
          } else {
            const int i = r32 * 32 + rg * 16 + q * 4 + r;
            const int jc = c32 * 32 + cg * 16 + l16;
            if (i != jc) tr += d - __logf(ee + nsv[rg][r]);
          }
        }
      }
    pos += scr * tr;
    if (mirror) pos += scc * tc;
  }

#pragma unroll
  for (int m = 1; m < 64; m <<= 1) pos += __shfl_xor(pos, m, 64);
  if (lane == 0) s_pos[w] = pos;
  __syncthreads();
  if (tid == 0)
    atomicAdd(out, -(s_pos[0] + s_pos[1] + s_pos[2] + s_pos[3]));
}

extern "C" void kernel_launch(void* const* d_in, const int* in_sizes, int n_in,
                              void* d_out, int out_size, void* d_ws,
                              size_t ws_size, hipStream_t stream) {
  const float* feat = (const float*)d_in[0];
  const int* binds = (const int*)d_in[1];
  const int* sinds = (const int*)d_in[2];
  const int* labels = (const int*)d_in[3];
  float* out = (float*)d_out;
  unsigned short* FT = (unsigned short*)d_ws;            // 4 MB  [256][8192]
  unsigned short* F2 = FT + (size_t)kC * kM;             // 4 MB  fragment fmt
  float* ns = (float*)(F2 + (size_t)kM * kC);            // 32 KB [8192]
  int* nact = (int*)(ns + kM);                           // 4 B (+pad)
  float* cscale = (float*)(nact + 8);                    // 128 B [32]
  ushort2* list = (ushort2*)(cscale + 32);               // 256 KB [65536]
  int* nneg = (int*)(list + 65536);                      // 4 B (+pad)
  ushort2* neglist = (ushort2*)(nneg + 8);               // 2 KB [512]

  k_prep<<<64, 256, 0, stream>>>(labels, ns, out, out_size, nact, list,
                                 cscale, nneg, neglist);
  k_gather<<<dim3(8, kC), 256, 0, stream>>>(feat, binds, sinds, FT);
  k_norm<<<kM / 32, 256, 0, stream>>>(FT, F2);
  k_neg<<<512, 512, 0, stream>>>(F2, nneg, neglist, ns);
  k_pos<<<512, 256, 0, stream>>>(F2, ns, nact, list, cscale, out);
}

// Round 12
// 161.169 us; speedup vs baseline: 1.1644x; 1.0128x over previous
//
#include <hip/hip_runtime.h>
#include <hip/hip_bf16.h>

// DenseContrastiveLossV2 on MI355X — round 13 (consolidation).
// Round-12: symmetric k_pos = -2.1us (165.3 -> 163.2). All structural
// levers spent; ~92us/iter is harness fillBufferAligned (immovable), our
// kernels ~71us vs ~35us component-floor sum, with the gap spread thinly.
// This round, low-risk only:
//  (1) k_prep merged INTO k_gather (grid (9,256); x==8 blocks run prep):
//      one fewer launch, prep runs parallel with gather instead of serial.
//  (2) k_pos grid 512 -> 768: nact~2816 tiles over 3072 workers -> <=1
//      tile/wave (was 1.375 -> wall set by 2-tile waves).
//  (3) k_norm / k_neg / k_pos bodies byte-identical to round 12 (passed).

namespace {

constexpr int kC = 256;
constexpr int kHW = 96 * 96;   // 9216
constexpr int kT = 32;
constexpr int kV = 256;
constexpr int kM = kT * kV;    // 8192

typedef __attribute__((ext_vector_type(8))) short short8;  // 8 bf16
typedef __attribute__((ext_vector_type(4))) float f32x4;

__device__ inline unsigned short f2bf(float x) {
  __hip_bfloat16 h = __float2bfloat16(x);
  return __builtin_bit_cast(unsigned short, h);
}
__device__ inline float bf2f(unsigned short u) {
  unsigned int v = ((unsigned int)u) << 16;
  return __builtin_bit_cast(float, v);
}
// exp(2a-2) = exp2(a*2log2e - 2log2e); one fma + native v_exp_f32.
__device__ inline float exp_2am2(float a) {
  return exp2f(fmaf(a, 2.8853900818f, -2.8853900818f));
}
__device__ inline void load_lds16(const unsigned short* g, unsigned short* l) {
  __builtin_amdgcn_global_load_lds(
      (const __attribute__((address_space(1))) void*)g,
      (__attribute__((address_space(3))) void*)l, 16, 0, 0);
}

// F2 fragment layout: for 16-vec group g, k-group ks (k = ks*32+q*8+e),
// lane (q*16+l16) stores elems e=0..7 of F[v=g*16+l16][c=ks*32+q*8+e].
// Slot offset in shorts: ((g*8+ks)<<9) + ((q*16+l16)<<3). One fragment =
// one 16B coalesced access; a g-group (16 rows x 256 k) = 8 KB contiguous.

// Stage one 2-g-group tile (32 cols x 256 k = 16 KB) into LDS, 512 thr.
__device__ inline void stage_ct(const unsigned short* __restrict__ F2,
                                unsigned short* lds, int g0, int tid) {
#pragma unroll
  for (int i = 0; i < 2; ++i) {
    const int nslot = i * 512 + tid;  // 16B slots 0..1023
    load_lds16(F2 + (((size_t)g0 * 8) << 9) + ((size_t)nslot << 3),
               lds + ((size_t)nslot << 3));
  }
}
// Stage 4 g-groups (64 rows, 32 KB) across both Bt buffers (prologue only).
__device__ inline void stage_a(const unsigned short* __restrict__ F2,
                               unsigned short* lds, int g0, int tid) {
#pragma unroll
  for (int i = 0; i < 4; ++i) {
    const int nslot = i * 512 + tid;  // 16B slots 0..2047
    load_lds16(F2 + (((size_t)g0 * 8) << 9) + ((size_t)nslot << 3),
               lds + ((size_t)nslot << 3));
  }
}

}  // namespace

// ---------------- K0: gather (+ fused prep on x==8) ----------------
// grid (9, 256). x in [0,8): gather block (b, c). x == 8: prep —
// y<32 blocks zero ns (1 store/thread); y==0 additionally zeroes out and
// builds cscale + symmetric pos list + neg t-pair list.
__global__ __launch_bounds__(256) void k_gather(
    const float* __restrict__ feat, const int* __restrict__ binds,
    const int* __restrict__ sinds, unsigned short* __restrict__ FT,
    const int* __restrict__ labels, float* __restrict__ ns,
    float* __restrict__ out, int out_size, int* __restrict__ nact,
    ushort2* __restrict__ list, float* __restrict__ cscale,
    int* __restrict__ nneg, ushort2* __restrict__ neglist) {
  const int tid = (int)threadIdx.x;
  const int b = (int)blockIdx.x;   // 0..8
  if (b == 8) {  // ---------------- fused prep path ----------------
    const int y = (int)blockIdx.y;
    if (y < 32) ns[y * 256 + tid] = 0.f;
    if (y != 0) return;
    __shared__ int s_lab[kT];
    if (tid < kT) s_lab[tid] = labels[tid];
    if (tid == 0) {
      *nact = 0;
      *nneg = 0;
    }
    for (int i = tid; i < out_size; i += 256) out[i] = 0.f;
    __syncthreads();
    if (tid < kT) {
      int m = 0;
      for (int u = 0; u < kT; ++u) m += (s_lab[u] == s_lab[tid]) ? 1 : 0;
      cscale[tid] = 1.f / ((float)(m * kV - 1) * (float)kM);
    }
    for (int p = tid; p < kT * kT; p += 256) {
      const int ti = p >> 5, tj = p & 31;
      if (s_lab[ti] == s_lab[tj]) {
        if (ti < tj) {
          // cross t-pair: 64 sub-tiles, all mirrored (i != j guaranteed).
          int base = atomicAdd(nact, 64);
#pragma unroll
          for (int a = 0; a < 8; ++a)
#pragma unroll
            for (int bb = 0; bb < 8; ++bb) {
              ushort2 e;
              e.x = (unsigned short)(ti * 8 + a);
              e.y = (unsigned short)((tj * 8 + bb) | 0x8000);
              list[base + a * 8 + bb] = e;
            }
        } else if (ti == tj) {
          // diagonal t: a<b mirrored (28) + a==b un-mirrored w/ i!=j (8).
          int base = atomicAdd(nact, 36);
          int k = 0;
          for (int a = 0; a < 8; ++a) {
            ushort2 d;
            d.x = (unsigned short)(ti * 8 + a);
            d.y = (unsigned short)(ti * 8 + a);  // mirror=0
            list[base + k++] = d;
            for (int bb = a + 1; bb < 8; ++bb) {
              ushort2 e;
              e.x = (unsigned short)(ti * 8 + a);
              e.y = (unsigned short)((ti * 8 + bb) | 0x8000);
              list[base + k++] = e;
            }
          }
        }
      } else if (ti < tj) {  // negative t-pair (upper triangle)
        int idx = atomicAdd(nneg, 1);
        ushort2 e;
        e.x = (unsigned short)ti;
        e.y = (unsigned short)tj;
        neglist[idx] = e;
      }
    }
    return;
  }
  // ---------------- gather path (unchanged) ----------------
  const int c = (int)blockIdx.y;   // 0..255
  __shared__ alignas(16) float row[kHW];
  __shared__ int s_match[kT + 1];
  if (tid == 0) {
    int cnt = 0;
    for (int t = 0; t < kT; ++t)
      if (binds[t] == b) s_match[1 + cnt++] = t;
    s_match[0] = cnt;
  }
  __syncthreads();
  const int cnt = s_match[0];
  if (cnt == 0) return;
  const float4* src4 = (const float4*)(feat + ((size_t)b * kC + c) * kHW);
  for (int i = tid; i < kHW / 4; i += 256) ((float4*)row)[i] = src4[i];
  __syncthreads();
  unsigned short* dst = FT + (size_t)c * kM;
  for (int mi = 1; mi <= cnt; ++mi) {
    const int t = s_match[mi];
    const int p = sinds[t * kV + tid];
    dst[t * kV + tid] = f2bf(row[p]);
  }
}

// ---------------- K2: transpose + normalize -> F2 fragment layout ---------
__global__ __launch_bounds__(256) void k_norm(
    const unsigned short* __restrict__ FT, unsigned short* __restrict__ F2) {
  constexpr int PAD = 40;  // 32 vecs + 8 pad (80 B rows: breaks bank aliasing)
  const int v0 = (int)blockIdx.x * 32;
  __shared__ alignas(16) unsigned short tile[kC][PAD];
  __shared__ float part[8][32];
  __shared__ float s_inv[32];
  const int tid = (int)threadIdx.x;
  {
    const int p4 = tid & 3, cb = tid >> 2;  // 4x16B per 64B c-row
    for (int c = cb; c < kC; c += 64) {
      int4 d = *(const int4*)(FT + (size_t)c * kM + v0 + p4 * 8);
      *(int4*)&tile[c][p4 * 8] = d;
    }
  }
  __syncthreads();
  {
    const int v = tid & 31, oct = tid >> 5;
    float ss = 0.f;
    for (int c = oct * 32; c < oct * 32 + 32; ++c) {
      float x = bf2f(tile[c][v]);
      ss += x * x;
    }
    part[oct][v] = ss;
  }
  __syncthreads();
  if (tid < 32) {
    float ss = 0.f;
#pragma unroll
    for (int o = 0; o < 8; ++o) ss += part[o][tid];
    s_inv[tid] = 1.0f / fmaxf(sqrtf(ss), 1e-12f);
  }
  __syncthreads();
#pragma unroll
  for (int p = 0; p < 4; ++p) {
    const int slot = p * 256 + tid;  // 0..1023
    const int l16s = slot & 15;
    const int qs = (slot >> 4) & 3;
    const int kss = (slot >> 6) & 7;
    const int gl = slot >> 9;  // 0..1
    const int vloc = gl * 16 + l16s;
    const int c0 = kss * 32 + qs * 8;
    const float inv = s_inv[vloc];
    alignas(16) unsigned short o[8];
#pragma unroll
    for (int k = 0; k < 8; ++k) o[k] = f2bf(bf2f(tile[c0 + k][vloc]) * inv);
    *(int4*)(F2 + ((size_t)(((v0 >> 4) + gl) * 8 + kss) << 9) +
             ((qs * 16 + l16s) << 3)) = *(const int4*)o;
  }
}

// ---------------- K3: negative sweep (triangle t-pairs) -> ns -------------
// (unchanged from round 11/12 — passed)
__global__ __launch_bounds__(512, 2) void k_neg(
    const unsigned short* __restrict__ F2, const int* __restrict__ nneg,
    const ushort2* __restrict__ neglist, float* __restrict__ ns) {
  const int tid = (int)threadIdx.x;
  const int w = tid >> 6, lane = tid & 63, q = lane >> 4, l16 = lane & 15;
  __shared__ alignas(16) unsigned short Bt[2][8192];  // 2 x 16 KB
  __shared__ float colacc[256];
  const int n = *nneg;
  const int laneofs = (q * 16 + l16) << 3;  // fragment lane offset (shorts)

  for (int job = (int)blockIdx.x; job < n; job += (int)gridDim.x) {
    const ushort2 e = neglist[job];
    const int ti = e.x, tj = e.y;
    if (tid < 256) colacc[tid] = 0.f;

    // A prologue: 4 passes x 32 KB through both Bt buffers; af LDS-sourced
    // then overwritten => register-resident (round-6 mechanism).
    short8 af[2][8];
#pragma unroll 1
    for (int p = 0; p < 4; ++p) {
      stage_a(F2, &Bt[0][0], ti * 16 + p * 4, tid);
      __syncthreads();  // staging drained (vmcnt(0) before barrier)
      if ((w >> 1) == p) {
        const int lg = (w & 1) * 2;  // local g-group 0 or 2
#pragma unroll
        for (int rg = 0; rg < 2; ++rg)
#pragma unroll
          for (int ks = 0; ks < 8; ++ks)
            af[rg][ks] = *(const short8*)(
                &Bt[0][0] + ((size_t)((lg + rg) * 8 + ks) << 9) + laneofs);
      }
      __syncthreads();  // readers done before next pass overwrites
    }

    // B ct-loop: 8 tiles of 32 cols, double-buffered (T3 order).
    stage_ct(F2, &Bt[0][0], tj * 16, tid);  // prologue prefetch ct0
    float rowacc[2][4] = {};
    int cur = 0;
#pragma unroll 1
    for (int ct = 0; ct < 8; ++ct) {
      __syncthreads();  // drains stage(ct); prev-tile readers are done
      if (ct < 7) stage_ct(F2, &Bt[cur ^ 1][0], tj * 16 + (ct + 1) * 2, tid);
      const unsigned short* bbase = &Bt[cur][0] + laneofs;
      f32x4 a00 = {0.f, 0.f, 0.f, 0.f}, a01 = a00, a10 = a00, a11 = a00;
#pragma unroll
      for (int ks = 0; ks < 8; ++ks) {
        short8 b0 = *(const short8*)(bbase + ((size_t)ks << 9));
        short8 b1 = *(const short8*)(bbase + ((size_t)(8 + ks) << 9));
        a00 = __builtin_amdgcn_mfma_f32_16x16x32_bf16(af[0][ks], b0, a00,
                                                      0, 0, 0);
        a01 = __builtin_amdgcn_mfma_f32_16x16x32_bf16(af[0][ks], b1, a01,
                                                      0, 0, 0);
        a10 = __builtin_amdgcn_mfma_f32_16x16x32_bf16(af[1][ks], b0, a10,
                                                      0, 0, 0);
        a11 = __builtin_amdgcn_mfma_f32_16x16x32_bf16(af[1][ks], b1, a11,
                                                      0, 0, 0);
      }
      float col0 = 0.f, col1 = 0.f;
#pragma unroll
      for (int r = 0; r < 4; ++r) {
        float e00 = exp_2am2(a00[r]), e01 = exp_2am2(a01[r]);
        float e10 = exp_2am2(a10[r]), e11 = exp_2am2(a11[r]);
        rowacc[0][r] += e00 + e01;
        rowacc[1][r] += e10 + e11;
        col0 += e00 + e10;
        col1 += e01 + e11;
      }
      col0 += __shfl_xor(col0, 16, 64);
      col0 += __shfl_xor(col0, 32, 64);
      col1 += __shfl_xor(col1, 16, 64);
      col1 += __shfl_xor(col1, 32, 64);
      if (q == 0) {
        atomicAdd(&colacc[ct * 32 + l16], col0);
        atomicAdd(&colacc[ct * 32 + 16 + l16], col1);
      }
      cur ^= 1;
    }
    __syncthreads();  // colacc complete
    if (tid < 256) atomicAdd(&ns[tj * 256 + tid], colacc[tid]);
#pragma unroll
    for (int rg = 0; rg < 2; ++rg)
#pragma unroll
      for (int r = 0; r < 4; ++r) {
        float v = rowacc[rg][r];
        v += __shfl_xor(v, 1, 64);
        v += __shfl_xor(v, 2, 64);
        v += __shfl_xor(v, 4, 64);
        v += __shfl_xor(v, 8, 64);
        if (l16 == 0)
          atomicAdd(&ns[ti * 256 + w * 32 + rg * 16 + q * 4 + r], v);
      }
    __syncthreads();  // flush done before next job resets colacc
  }
}

// ---------------- K4: positive sweep -> loss (symmetric, list-driven) -----
// (body unchanged from round 12 — passed; grid 768 for 1 tile/wave balance)
__global__ __launch_bounds__(256, 2) void k_pos(
    const unsigned short* __restrict__ F2, const float* __restrict__ ns,
    const int* __restrict__ nact, const ushort2* __restrict__ list,
    const float* __restrict__ cscale, float* __restrict__ out) {
  const int tid = (int)threadIdx.x;
  const int w = tid >> 6, lane = tid & 63, q = lane >> 4, l16 = lane & 15;
  __shared__ float s_pos[4];
  const int n = *nact;
  const unsigned short* lanep = F2 + ((q * 16 + l16) << 3);

  float pos = 0.f;
  for (int idx = (int)blockIdx.x * 4 + w; idx < n;
       idx += (int)gridDim.x * 4) {
    const ushort2 e = list[idx];
    const int r32 = e.x;
    const int c32 = e.y & 0x7fff;
    const bool mirror = (e.y & 0x8000) != 0;
    const int ga = r32 * 2, gb = c32 * 2;
    short8 af[2][8], bf[2][8];
#pragma unroll
    for (int rg = 0; rg < 2; ++rg)
#pragma unroll
      for (int ks = 0; ks < 8; ++ks) {
        af[rg][ks] =
            *(const short8*)(lanep + ((size_t)((ga + rg) * 8 + ks) << 9));
        bf[rg][ks] =
            *(const short8*)(lanep + ((size_t)((gb + rg) * 8 + ks) << 9));
      }
    float nsv[2][4];
#pragma unroll
    for (int rg = 0; rg < 2; ++rg)
#pragma unroll
      for (int r = 0; r < 4; ++r)
        nsv[rg][r] = ns[r32 * 32 + rg * 16 + q * 4 + r];
    float nsc[2];
    nsc[0] = ns[c32 * 32 + l16];
    nsc[1] = ns[c32 * 32 + 16 + l16];
    const float scr = cscale[r32 >> 3];
    const float scc = cscale[c32 >> 3];

    f32x4 a00 = {0.f, 0.f, 0.f, 0.f}, a01 = a00, a10 = a00, a11 = a00;
#pragma unroll
    for (int ks = 0; ks < 8; ++ks) {
      a00 = __builtin_amdgcn_mfma_f32_16x16x32_bf16(af[0][ks], bf[0][ks], a00,
                                                    0, 0, 0);
      a01 = __builtin_amdgcn_mfma_f32_16x16x32_bf16(af[0][ks], bf[1][ks], a01,
                                                    0, 0, 0);
      a10 = __builtin_amdgcn_mfma_f32_16x16x32_bf16(af[1][ks], bf[0][ks], a10,
                                                    0, 0, 0);
      a11 = __builtin_amdgcn_mfma_f32_16x16x32_bf16(af[1][ks], bf[1][ks], a11,
                                                    0, 0, 0);
    }
    float tr = 0.f, tc = 0.f;
#pragma unroll
    for (int rg = 0; rg < 2; ++rg)
#pragma unroll
      for (int cg = 0; cg < 2; ++cg) {
        const f32x4 acc =
            (rg == 0) ? (cg == 0 ? a00 : a01) : (cg == 0 ? a10 : a11);
#pragma unroll
        for (int r = 0; r < 4; ++r) {
          const float d = fmaf(acc[r], 2.f, -2.f);
          const float ee = exp_2am2(acc[r]);
          if (mirror) {
            tr += d - __logf(ee + nsv[rg][r]);
            tc += d - __logf(ee + nsc[cg]);
          } else {
            const int i = r32 * 32 + rg * 16 + q * 4 + r;
            const int jc = c32 * 32 + cg * 16 + l16;
            if (i != jc) tr += d - __logf(ee + nsv[rg][r]);
          }
        }
      }
    pos += scr * tr;
    if (mirror) pos += scc * tc;
  }

#pragma unroll
  for (int m = 1; m < 64; m <<= 1) pos += __shfl_xor(pos, m, 64);
  if (lane == 0) s_pos[w] = pos;
  __syncthreads();
  if (tid == 0)
    atomicAdd(out, -(s_pos[0] + s_pos[1] + s_pos[2] + s_pos[3]));
}

extern "C" void kernel_launch(void* const* d_in, const int* in_sizes, int n_in,
                              void* d_out, int out_size, void* d_ws,
                              size_t ws_size, hipStream_t stream) {
  const float* feat = (const float*)d_in[0];
  const int* binds = (const int*)d_in[1];
  const int* sinds = (const int*)d_in[2];
  const int* labels = (const int*)d_in[3];
  float* out = (float*)d_out;
  unsigned short* FT = (unsigned short*)d_ws;            // 4 MB  [256][8192]
  unsigned short* F2 = FT + (size_t)kC * kM;             // 4 MB  fragment fmt
  float* ns = (float*)(F2 + (size_t)kM * kC);            // 32 KB [8192]
  int* nact = (int*)(ns + kM);                           // 4 B (+pad)
  float* cscale = (float*)(nact + 8);                    // 128 B [32]
  ushort2* list = (ushort2*)(cscale + 32);               // 256 KB [65536]
  int* nneg = (int*)(list + 65536);                      // 4 B (+pad)
  ushort2* neglist = (ushort2*)(nneg + 8);               // 2 KB [512]

  k_gather<<<dim3(9, kC), 256, 0, stream>>>(feat, binds, sinds, FT, labels,
                                            ns, out, out_size, nact, list,
                                            cscale, nneg, neglist);
  k_norm<<<kM / 32, 256, 0, stream>>>(FT, F2);
  k_neg<<<512, 512, 0, stream>>>(F2, nneg, neglist, ns);
  k_pos<<<768, 256, 0, stream>>>(F2, ns, nact, list, cscale, out);
}